// Round 1
// baseline (3532.936 us; speedup 1.0000x reference)
//
#include <hip/hip_runtime.h>
#include <cstdint>

// Model dims (fixed for this problem)
//  L=128, B=64, DM=1024, H=256, F=512, HID=256, MEM=768, N=B*L=8192, NC=6, R=8, NB=30, WIN=10

// ---------------------------------------------------------------------------
// Generic fp32 GEMM: C = A(MxK) * B + bias,  B either (K x N) [NN] or (N x K) [NT]
// Tiles: 128x128x16, 256 threads, 8x8 per thread. All dims assumed multiples.
// Batched via blockIdx.z with element strides sA/sB/sC/sBias.
// ---------------------------------------------------------------------------
#define BMg 128
#define BNg 128
#define BKg 16

template<bool TRANSB, bool HASBIAS, bool ACCUM, bool RELU>
__global__ __launch_bounds__(256) void gemm_k(
    const float* __restrict__ A, const float* __restrict__ Bm,
    const float* __restrict__ bias, float* __restrict__ C,
    int M, int Nd, int K, long sA, long sB, long sC, long sBias)
{
  const int bz = blockIdx.z;
  A += (long)bz * sA;
  Bm += (long)bz * sB;
  C += (long)bz * sC;
  if (HASBIAS) bias += (long)bz * sBias;

  const int bn = blockIdx.x * BNg;
  const int bm = blockIdx.y * BMg;

  __shared__ float As[BKg][BMg + 4];
  __shared__ float Bs[BKg][BNg + 4];

  const int tid = threadIdx.x;
  const int tm = (tid >> 4) << 3;   // 0..120
  const int tn = (tid & 15) << 3;   // 0..120

  float acc[8][8];
#pragma unroll
  for (int r = 0; r < 8; ++r)
#pragma unroll
    for (int c = 0; c < 8; ++c) acc[r][c] = 0.f;

  const int lr = tid >> 1;          // 0..127 (row for A / NT-B loads)
  const int lk = (tid & 1) * 8;     // 0 or 8
  const int bkr = tid >> 4;         // 0..15 (k row for NN-B loads)
  const int bnc = (tid & 15) * 8;   // 0..120

  for (int k0 = 0; k0 < K; k0 += BKg) {
    {
      const float* ap = A + (long)(bm + lr) * K + k0 + lk;
      float4 a0 = *(const float4*)ap;
      float4 a1 = *(const float4*)(ap + 4);
      As[lk + 0][lr] = a0.x; As[lk + 1][lr] = a0.y; As[lk + 2][lr] = a0.z; As[lk + 3][lr] = a0.w;
      As[lk + 4][lr] = a1.x; As[lk + 5][lr] = a1.y; As[lk + 6][lr] = a1.z; As[lk + 7][lr] = a1.w;
    }
    if (TRANSB) {
      const float* bp = Bm + (long)(bn + lr) * K + k0 + lk;
      float4 b0 = *(const float4*)bp;
      float4 b1 = *(const float4*)(bp + 4);
      Bs[lk + 0][lr] = b0.x; Bs[lk + 1][lr] = b0.y; Bs[lk + 2][lr] = b0.z; Bs[lk + 3][lr] = b0.w;
      Bs[lk + 4][lr] = b1.x; Bs[lk + 5][lr] = b1.y; Bs[lk + 6][lr] = b1.z; Bs[lk + 7][lr] = b1.w;
    } else {
      const float* bp = Bm + (long)(k0 + bkr) * Nd + bn + bnc;
      float4 b0 = *(const float4*)bp;
      float4 b1 = *(const float4*)(bp + 4);
      *(float4*)&Bs[bkr][bnc] = b0;
      *(float4*)&Bs[bkr][bnc + 4] = b1;
    }
    __syncthreads();
#pragma unroll
    for (int kk = 0; kk < BKg; ++kk) {
      float4 a0 = *(const float4*)&As[kk][tm];
      float4 a1 = *(const float4*)&As[kk][tm + 4];
      float4 b0 = *(const float4*)&Bs[kk][tn];
      float4 b1 = *(const float4*)&Bs[kk][tn + 4];
      float av[8] = {a0.x, a0.y, a0.z, a0.w, a1.x, a1.y, a1.z, a1.w};
      float bv[8] = {b0.x, b0.y, b0.z, b0.w, b1.x, b1.y, b1.z, b1.w};
#pragma unroll
      for (int r = 0; r < 8; ++r)
#pragma unroll
        for (int c = 0; c < 8; ++c)
          acc[r][c] = fmaf(av[r], bv[c], acc[r][c]);
    }
    __syncthreads();
  }

#pragma unroll
  for (int r = 0; r < 8; ++r) {
    float* cp = C + (long)(bm + tm + r) * Nd + bn + tn;
#pragma unroll
    for (int c = 0; c < 8; ++c) {
      float v = acc[r][c];
      if (HASBIAS) v += bias[bn + tn + c];
      if (ACCUM) v += cp[c];
      if (RELU) v = fmaxf(v, 0.f);
      cp[c] = v;
    }
  }
}

// ---------------------------------------------------------------------------
// bf16 helpers (manual, RNE)
// ---------------------------------------------------------------------------
__device__ __forceinline__ unsigned short f2bf(float f) {
  unsigned u = __float_as_uint(f);
  u += 0x7fffu + ((u >> 16) & 1u);
  return (unsigned short)(u >> 16);
}
__device__ __forceinline__ float bfu(unsigned short v) {
  return __uint_as_float(((unsigned)v) << 16);
}
__device__ __forceinline__ float sigf(float x) { return 1.f / (1.f + expf(-x)); }

// Pack Whh (2,1024,256) -> (2,256 k,256 i) ushort4 of the 4 gate weights (i,f,g,o)
__global__ __launch_bounds__(256) void pack_whh_k(const float* __restrict__ Whh,
                                                  ushort4* __restrict__ Wp) {
  const int idx = blockIdx.x * 256 + threadIdx.x;  // [0, 131072)
  const int d = idx >> 16;
  const int k = (idx >> 8) & 255;
  const int i = idx & 255;
  const float* W = Whh + (long)d * 1024 * 256;
  ushort4 u;
  u.x = f2bf(W[(0 * 256 + i) * 256 + k]);
  u.y = f2bf(W[(1 * 256 + i) * 256 + k]);
  u.z = f2bf(W[(2 * 256 + i) * 256 + k]);
  u.w = f2bf(W[(3 * 256 + i) * 256 + k]);
  Wp[idx] = u;
}

// ---------------------------------------------------------------------------
// LSTM layer (both directions): one WG per (dir, batch-row). Gates precomputed
// in Xg = x@Wih^T + b. h kept in LDS (double buffered), c in regs.
// out: (L,B,512) with [0:256)=fwd, [256:512)=bwd.
// ---------------------------------------------------------------------------
__global__ __launch_bounds__(256) void lstm_k(
    const float* __restrict__ Xg,    // (2, 8192, 1024)
    const ushort4* __restrict__ Wp,  // (2, 256, 256)
    float* __restrict__ out)         // (128, 64, 512)
{
  const int bx = blockIdx.x;     // 0..127
  const int d = bx >> 6, b = bx & 63;
  const int i = threadIdx.x;     // 0..255
  __shared__ float hbuf[2][256];
  hbuf[0][i] = 0.f;
  float c = 0.f;
  const ushort4* W = Wp + (long)d * 65536;
  const float* X = Xg + (long)d * 8192 * 1024;
  __syncthreads();
  int cur = 0;
  for (int step = 0; step < 128; ++step) {
    const int t = d ? (127 - step) : step;
    const float* xr = X + (long)(t * 64 + b) * 1024;
    float p0 = xr[i], p1 = xr[256 + i], p2 = xr[512 + i], p3 = xr[768 + i];
#pragma unroll 1
    for (int k4 = 0; k4 < 256; k4 += 8) {
      float4 h4a = *(const float4*)&hbuf[cur][k4];
      float4 h4b = *(const float4*)&hbuf[cur][k4 + 4];
      float hk[8] = {h4a.x, h4a.y, h4a.z, h4a.w, h4b.x, h4b.y, h4b.z, h4b.w};
#pragma unroll
      for (int j = 0; j < 8; ++j) {
        ushort4 w = W[(k4 + j) * 256 + i];
        p0 = fmaf(bfu(w.x), hk[j], p0);
        p1 = fmaf(bfu(w.y), hk[j], p1);
        p2 = fmaf(bfu(w.z), hk[j], p2);
        p3 = fmaf(bfu(w.w), hk[j], p3);
      }
    }
    const float ig = sigf(p0), fg = sigf(p1);
    const float gg = tanhf(p2), og = sigf(p3);
    c = fg * c + ig * gg;
    const float h = og * tanhf(c);
    hbuf[cur ^ 1][i] = h;
    out[(long)(t * 64 + b) * 512 + (d << 8) + i] = h;
    cur ^= 1;
    __syncthreads();
  }
}

// ---------------------------------------------------------------------------
// Edge attention: softmax over source axis s (axis 0 of scale (L,B,L)),
// then window mask (1 / 1e-10) renormalization. scores: (B, t, s)
// ---------------------------------------------------------------------------
__global__ __launch_bounds__(128) void edge_softmax_k(const float* __restrict__ scale,
                                                      float* __restrict__ scores) {
  const int bx = blockIdx.x;            // b*128 + t
  const int b = bx >> 7, t = bx & 127;
  const int s = threadIdx.x;
  __shared__ float red[128];
  const float v = scale[((long)(s * 64 + b)) * 128 + t];
  red[s] = v; __syncthreads();
  for (int off = 64; off > 0; off >>= 1) { if (s < off) red[s] = fmaxf(red[s], red[s + off]); __syncthreads(); }
  const float m = red[0]; __syncthreads();
  const float e = expf(v - m);
  red[s] = e; __syncthreads();
  for (int off = 64; off > 0; off >>= 1) { if (s < off) red[s] += red[s + off]; __syncthreads(); }
  const float esum = red[0]; __syncthreads();
  const float alpha = e / esum;
  const int dd = s - t;
  const bool inwin = (dd <= 10) && (dd >= -10);
  const float masked = alpha * (inwin ? 1.0f : 1e-10f);
  red[s] = masked; __syncthreads();
  for (int off = 64; off > 0; off >>= 1) { if (s < off) red[s] += red[s + off]; __syncthreads(); }
  const float msum = red[0];
  scores[(long)bx * 128 + s] = inwin ? (masked / msum) : 0.f;
}

// x (conversation-major) from feats (time-major): xb[b*128+t] = feats[t*64+b]
__global__ __launch_bounds__(256) void xbuf_k(const float* __restrict__ feats,
                                              float* __restrict__ xb) {
  const int n = blockIdx.x;
  const int b = n >> 7, t = n & 127;
  const int tid = threadIdx.x;
  const float* src = feats + (long)(t * 64 + b) * 512;
  float* dst = xb + (long)n * 512;
  dst[tid] = src[tid];
  dst[tid + 256] = src[tid + 256];
}

// W_rel basis combination, output transposed for NN GEMM: Wrel2[f][r*256+o]
__global__ __launch_bounds__(256) void wrel_k(const float* __restrict__ basis,
                                              const float* __restrict__ comp,
                                              float* __restrict__ Wrel2) {
  const int f = blockIdx.x;     // 0..511
  const int o = threadIdx.x;    // 0..255
  __shared__ float cs[240];     // comp (8,30)
  if (o < 240) cs[o] = comp[o];
  __syncthreads();
  float acc[8];
#pragma unroll
  for (int r = 0; r < 8; ++r) acc[r] = 0.f;
  for (int bb = 0; bb < 30; ++bb) {
    const float v = basis[((long)bb * 512 + f) * 256 + o];
#pragma unroll
    for (int r = 0; r < 8; ++r) acc[r] = fmaf(cs[r * 30 + bb], v, acc[r]);
  }
#pragma unroll
  for (int r = 0; r < 8; ++r) Wrel2[(long)f * 2048 + r * 256 + o] = acc[r];
}

// RGCN message gather: h[n] = sum_{s in win} xrel[src, etype] * score + hroot[n]
__global__ __launch_bounds__(256) void rgcn_gather_k(
    const float* __restrict__ xrel, const float* __restrict__ scores,
    const float* __restrict__ hroot, const int* __restrict__ spk,
    float* __restrict__ h)
{
  const int n = blockIdx.x;
  const int b = n >> 7, t = n & 127;
  const int o = threadIdx.x;
  const int lo = max(t - 10, 0), hi = min(t + 10, 127);
  const int cnt = hi - lo + 1;
  __shared__ int spks[21];
  __shared__ float wv[21];
  __shared__ int spkt_s;
  if (o < cnt) {
    spks[o] = spk[(lo + o) * 64 + b];
    wv[o] = scores[((long)(b * 128 + t)) * 128 + lo + o];
  }
  if (o == 0) spkt_s = spk[t * 64 + b];
  __syncthreads();
  const int spkt = spkt_s;
  float acc = hroot[(long)n * 256 + o];
  for (int q = 0; q < cnt; ++q) {
    const int s = lo + q;
    const int et = spkt * 4 + spks[q] * 2 + ((t < s) ? 0 : 1);
    acc = fmaf(xrel[(((long)(b * 128 + s)) * 8 + et) * 256 + o], wv[q], acc);
  }
  h[(long)n * 256 + o] = acc;
}

// GraphConv neighbor aggregation (unweighted banded sum)
__global__ __launch_bounds__(256) void agg_k(const float* __restrict__ h,
                                             float* __restrict__ agg) {
  const int n = blockIdx.x;
  const int b = n >> 7, t = n & 127;
  const int o = threadIdx.x;
  const int lo = max(t - 10, 0), hi = min(t + 10, 127);
  float acc = 0.f;
  for (int s = lo; s <= hi; ++s) acc += h[((long)(b * 128 + s)) * 256 + o];
  agg[(long)n * 256 + o] = acc;
}

// em = concat(x, h2)
__global__ __launch_bounds__(256) void em_k(const float* __restrict__ xb,
                                            const float* __restrict__ h2,
                                            float* __restrict__ em) {
  const int n = blockIdx.x;
  const int tid = threadIdx.x;
  em[(long)n * 768 + tid] = xb[(long)n * 512 + tid];
  em[(long)n * 768 + 256 + tid] = xb[(long)n * 512 + 256 + tid];
  em[(long)n * 768 + 512 + tid] = h2[(long)n * 256 + tid];
}

// Matching attention probs: a = norm(softmax(tanh(dot*um^2)) * um) in-place
__global__ __launch_bounds__(128) void match_softmax_k(float* __restrict__ logits,
                                                       const float* __restrict__ umask) {
  const int bx = blockIdx.x;           // b*128 + t
  const int b = bx >> 7;
  const int s = threadIdx.x;
  __shared__ float red[128];
  float* row = logits + (long)bx * 128;
  const float um = umask[b * 128 + s];
  const float v = tanhf(row[s] * um * um);
  red[s] = v; __syncthreads();
  for (int off = 64; off > 0; off >>= 1) { if (s < off) red[s] = fmaxf(red[s], red[s + off]); __syncthreads(); }
  const float m = red[0]; __syncthreads();
  const float e = expf(v - m);
  red[s] = e; __syncthreads();
  for (int off = 64; off > 0; off >>= 1) { if (s < off) red[s] += red[s + off]; __syncthreads(); }
  const float es = red[0]; __syncthreads();
  const float p = (e / es) * um;
  red[s] = p; __syncthreads();
  for (int off = 64; off > 0; off >>= 1) { if (s < off) red[s] += red[s + off]; __syncthreads(); }
  const float ps = red[0];
  row[s] = p / ps;
}

// Final: out = log_softmax(hidden @ Ws + bs) ; one wave per row
__global__ __launch_bounds__(256) void final_k(const float* __restrict__ hidden,
                                               const float* __restrict__ Ws,
                                               const float* __restrict__ bs,
                                               float* __restrict__ out) {
  __shared__ float wsl[256 * 6];
  const int tid = threadIdx.x;
#pragma unroll
  for (int j = 0; j < 6; ++j) wsl[tid * 6 + j] = Ws[tid * 6 + j];
  __syncthreads();
  const int wave = tid >> 6, lane = tid & 63;
  const int n = blockIdx.x * 4 + wave;
  const float4 hv = *(const float4*)&hidden[(long)n * 256 + lane * 4];
  const float hvv[4] = {hv.x, hv.y, hv.z, hv.w};
  float a[6];
#pragma unroll
  for (int c = 0; c < 6; ++c) a[c] = 0.f;
#pragma unroll
  for (int j = 0; j < 4; ++j)
#pragma unroll
    for (int c = 0; c < 6; ++c)
      a[c] = fmaf(hvv[j], wsl[(lane * 4 + j) * 6 + c], a[c]);
#pragma unroll
  for (int off = 32; off > 0; off >>= 1)
#pragma unroll
    for (int c = 0; c < 6; ++c)
      a[c] += __shfl_xor(a[c], off, 64);
  if (lane == 0) {
    float v[6], m = -1e30f;
#pragma unroll
    for (int c = 0; c < 6; ++c) { v[c] = a[c] + bs[c]; m = fmaxf(m, v[c]); }
    float sum = 0.f;
#pragma unroll
    for (int c = 0; c < 6; ++c) sum += expf(v[c] - m);
    const float lse = m + logf(sum);
#pragma unroll
    for (int c = 0; c < 6; ++c) out[(long)n * 6 + c] = v[c] - lse;
  }
}

// ---------------------------------------------------------------------------
// Orchestration
// ---------------------------------------------------------------------------
extern "C" void kernel_launch(void* const* d_in, const int* in_sizes, int n_in,
                              void* d_out, int out_size, void* d_ws, size_t ws_size,
                              hipStream_t stream) {
  const float* U        = (const float*)d_in[0];   // (128,64,1024)
  const float* umask    = (const float*)d_in[1];   // (64,128)
  const float* Wih0     = (const float*)d_in[2];   // (2,1024,1024)
  const float* Whh0     = (const float*)d_in[3];   // (2,1024,256)
  const float* b0       = (const float*)d_in[4];   // (2,1024)
  const float* Wih1     = (const float*)d_in[5];   // (2,1024,512)
  const float* Whh1     = (const float*)d_in[6];   // (2,1024,256)
  const float* b1       = (const float*)d_in[7];   // (2,1024)
  const float* W_scalar = (const float*)d_in[8];   // (512,128)
  const float* basis    = (const float*)d_in[9];   // (30,512,256)
  const float* comp     = (const float*)d_in[10];  // (8,30)
  const float* W_root   = (const float*)d_in[11];  // (512,256)
  const float* b_rgcn   = (const float*)d_in[12];  // (256)
  const float* gc_W1    = (const float*)d_in[13];  // (256,256)
  const float* gc_W2    = (const float*)d_in[14];  // (256,256)
  const float* gc_b     = (const float*)d_in[15];  // (256)
  const float* Wm       = (const float*)d_in[16];  // (768,768)
  const float* bm       = (const float*)d_in[17];  // (768)
  const float* Wl       = (const float*)d_in[18];  // (768,256)
  const float* bl       = (const float*)d_in[19];  // (256)
  const float* Wsw      = (const float*)d_in[20];  // (256,6)
  const float* bsw      = (const float*)d_in[21];  // (6)
  const int*   speakers = (const int*)d_in[22];    // (128,64)
  // d_in[23..25] (edge_src/edge_dst/edge_mask) reconstructed structurally.

  float* ws = (float*)d_ws;
  // Workspace layout (float elements), regions reused across phases:
  float* gates   = ws + 0L;          // 16,777,216  X0/X1 gates -> xrel -> em/xtr
  float* feats   = ws + 16777216L;   //  4,194,304  layer1 output (t-major) -> att (spans next)
  float* xbuf    = ws + 20971520L;   //  4,194,304  x (b-major)
  float* feats0  = ws + 25165824L;   //  4,194,304  layer0 output -> h + agg
  float* scaleb  = ws + 29360128L;   //  1,048,576  scale -> logits -> hidden (spans next)
  float* scoresb = ws + 30408704L;   //  1,048,576
  float* wrel2   = ws + 31457280L;   //  1,048,576
  float* hroot   = ws + 32505856L;   //  2,097,152  hroot -> h2
  ushort4* wpack = (ushort4*)(ws + 34603008L);     // 2 layers x 131072 ushort4 (4 MB)

  float* xrel    = gates;
  float* hb      = feats0;
  float* aggb    = feats0 + 2097152L;
  float* h2b     = hroot;
  float* emb     = gates;
  float* xtrb    = gates + 6291456L;
  float* logitsb = scaleb;
  float* attb    = feats;            // 6,291,456 spans feats+xbuf (both dead by then)
  float* hiddenb = scaleb;           // 2,097,152 spans scaleb+scoresb (both dead)

  // --- pack recurrent weights (bf16, gate-interleaved) ---
  pack_whh_k<<<512, 256, 0, stream>>>(Whh0, wpack);
  pack_whh_k<<<512, 256, 0, stream>>>(Whh1, wpack + 131072);

  // --- layer 0: input gates + recurrence ---
  gemm_k<true, true, false, false><<<dim3(8, 64, 2), 256, 0, stream>>>(
      U, Wih0, b0, gates, 8192, 1024, 1024, 0L, 1048576L, 8388608L, 1024L);
  lstm_k<<<128, 256, 0, stream>>>(gates, wpack, feats0);

  // --- layer 1 ---
  gemm_k<true, true, false, false><<<dim3(8, 64, 2), 256, 0, stream>>>(
      feats0, Wih1, b1, gates, 8192, 1024, 512, 0L, 524288L, 8388608L, 1024L);
  lstm_k<<<128, 256, 0, stream>>>(gates, wpack + 131072, feats);

  // --- edge attention scores ---
  gemm_k<false, false, false, false><<<dim3(1, 64, 1), 256, 0, stream>>>(
      feats, W_scalar, nullptr, scaleb, 8192, 128, 512, 0L, 0L, 0L, 0L);
  edge_softmax_k<<<8192, 128, 0, stream>>>(scaleb, scoresb);

  // --- node features (b-major) + RGCN ---
  xbuf_k<<<8192, 256, 0, stream>>>(feats, xbuf);
  wrel_k<<<512, 256, 0, stream>>>(basis, comp, wrel2);
  gemm_k<false, true, false, false><<<dim3(2, 64, 1), 256, 0, stream>>>(
      xbuf, W_root, b_rgcn, hroot, 8192, 256, 512, 0L, 0L, 0L, 0L);
  gemm_k<false, false, false, false><<<dim3(16, 64, 1), 256, 0, stream>>>(
      xbuf, wrel2, nullptr, xrel, 8192, 2048, 512, 0L, 0L, 0L, 0L);
  rgcn_gather_k<<<8192, 256, 0, stream>>>(xrel, scoresb, hroot, speakers, hb);

  // --- GraphConv ---
  agg_k<<<8192, 256, 0, stream>>>(hb, aggb);
  gemm_k<false, true, false, false><<<dim3(2, 64, 1), 256, 0, stream>>>(
      hb, gc_W1, gc_b, h2b, 8192, 256, 256, 0L, 0L, 0L, 0L);
  gemm_k<false, false, true, false><<<dim3(2, 64, 1), 256, 0, stream>>>(
      aggb, gc_W2, nullptr, h2b, 8192, 256, 256, 0L, 0L, 0L, 0L);

  // --- matching attention ---
  em_k<<<8192, 256, 0, stream>>>(xbuf, h2b, emb);
  gemm_k<false, true, false, false><<<dim3(6, 64, 1), 256, 0, stream>>>(
      emb, Wm, bm, xtrb, 8192, 768, 768, 0L, 0L, 0L, 0L);
  gemm_k<true, false, false, false><<<dim3(1, 1, 64), 256, 0, stream>>>(
      xtrb, emb, nullptr, logitsb, 128, 128, 768, 98304L, 98304L, 16384L, 0L);
  match_softmax_k<<<8192, 128, 0, stream>>>(logitsb, umask);
  gemm_k<false, false, false, false><<<dim3(6, 1, 64), 256, 0, stream>>>(
      logitsb, emb, nullptr, attb, 128, 768, 128, 16384L, 98304L, 98304L, 0L);

  // --- classifier ---
  gemm_k<false, true, false, true><<<dim3(2, 64, 1), 256, 0, stream>>>(
      attb, Wl, bl, hiddenb, 8192, 256, 768, 0L, 0L, 0L, 0L);
  final_k<<<2048, 256, 0, stream>>>(hiddenb, Wsw, bsw, (float*)d_out);
}

// Round 2
// 2751.313 us; speedup vs baseline: 1.2841x; 1.2841x over previous
//
#include <hip/hip_runtime.h>
#include <cstdint>

// Model dims (fixed): L=128, B=64, DM=1024, H=256, F=512, HID=256, MEM=768,
// N=B*L=8192, NC=6, R=8, NB=30, WIN=10

typedef _Float16 h2_t __attribute__((ext_vector_type(2)));

// ---------------------------------------------------------------------------
// Generic fp32 GEMM: C = A(MxK) * B + bias,  B either (K x N) [NN] or (N x K) [NT]
// Tiles: 128x128x16, 256 threads, 8x8 per thread. All dims assumed multiples.
// ---------------------------------------------------------------------------
#define BMg 128
#define BNg 128
#define BKg 16

template<bool TRANSB, bool HASBIAS, bool ACCUM, bool RELU>
__global__ __launch_bounds__(256) void gemm_k(
    const float* __restrict__ A, const float* __restrict__ Bm,
    const float* __restrict__ bias, float* __restrict__ C,
    int M, int Nd, int K, long sA, long sB, long sC, long sBias)
{
  const int bz = blockIdx.z;
  A += (long)bz * sA;
  Bm += (long)bz * sB;
  C += (long)bz * sC;
  if (HASBIAS) bias += (long)bz * sBias;

  const int bn = blockIdx.x * BNg;
  const int bm = blockIdx.y * BMg;

  __shared__ float As[BKg][BMg + 4];
  __shared__ float Bs[BKg][BNg + 4];

  const int tid = threadIdx.x;
  const int tm = (tid >> 4) << 3;
  const int tn = (tid & 15) << 3;

  float acc[8][8];
#pragma unroll
  for (int r = 0; r < 8; ++r)
#pragma unroll
    for (int c = 0; c < 8; ++c) acc[r][c] = 0.f;

  const int lr = tid >> 1;
  const int lk = (tid & 1) * 8;
  const int bkr = tid >> 4;
  const int bnc = (tid & 15) * 8;

  for (int k0 = 0; k0 < K; k0 += BKg) {
    {
      const float* ap = A + (long)(bm + lr) * K + k0 + lk;
      float4 a0 = *(const float4*)ap;
      float4 a1 = *(const float4*)(ap + 4);
      As[lk + 0][lr] = a0.x; As[lk + 1][lr] = a0.y; As[lk + 2][lr] = a0.z; As[lk + 3][lr] = a0.w;
      As[lk + 4][lr] = a1.x; As[lk + 5][lr] = a1.y; As[lk + 6][lr] = a1.z; As[lk + 7][lr] = a1.w;
    }
    if (TRANSB) {
      const float* bp = Bm + (long)(bn + lr) * K + k0 + lk;
      float4 b0 = *(const float4*)bp;
      float4 b1 = *(const float4*)(bp + 4);
      Bs[lk + 0][lr] = b0.x; Bs[lk + 1][lr] = b0.y; Bs[lk + 2][lr] = b0.z; Bs[lk + 3][lr] = b0.w;
      Bs[lk + 4][lr] = b1.x; Bs[lk + 5][lr] = b1.y; Bs[lk + 6][lr] = b1.z; Bs[lk + 7][lr] = b1.w;
    } else {
      const float* bp = Bm + (long)(k0 + bkr) * Nd + bn + bnc;
      float4 b0 = *(const float4*)bp;
      float4 b1 = *(const float4*)(bp + 4);
      *(float4*)&Bs[bkr][bnc] = b0;
      *(float4*)&Bs[bkr][bnc + 4] = b1;
    }
    __syncthreads();
#pragma unroll
    for (int kk = 0; kk < BKg; ++kk) {
      float4 a0 = *(const float4*)&As[kk][tm];
      float4 a1 = *(const float4*)&As[kk][tm + 4];
      float4 b0 = *(const float4*)&Bs[kk][tn];
      float4 b1 = *(const float4*)&Bs[kk][tn + 4];
      float av[8] = {a0.x, a0.y, a0.z, a0.w, a1.x, a1.y, a1.z, a1.w};
      float bv[8] = {b0.x, b0.y, b0.z, b0.w, b1.x, b1.y, b1.z, b1.w};
#pragma unroll
      for (int r = 0; r < 8; ++r)
#pragma unroll
        for (int c = 0; c < 8; ++c)
          acc[r][c] = fmaf(av[r], bv[c], acc[r][c]);
    }
    __syncthreads();
  }

#pragma unroll
  for (int r = 0; r < 8; ++r) {
    float* cp = C + (long)(bm + tm + r) * Nd + bn + tn;
#pragma unroll
    for (int c = 0; c < 8; ++c) {
      float v = acc[r][c];
      if (HASBIAS) v += bias[bn + tn + c];
      if (ACCUM) v += cp[c];
      if (RELU) v = fmaxf(v, 0.f);
      cp[c] = v;
    }
  }
}

// ---------------------------------------------------------------------------
// helpers
// ---------------------------------------------------------------------------
__device__ __forceinline__ float sigf(float x) { return 1.f / (1.f + expf(-x)); }

__device__ __forceinline__ float fdot2f(h2_t a, h2_t b, float c) {
#if __has_builtin(__builtin_amdgcn_fdot2)
  return __builtin_amdgcn_fdot2(a, b, c, false);
#else
  return fmaf((float)a.x, (float)b.x, fmaf((float)a.y, (float)b.y, c));
#endif
}

// Pack Whh (2,1024,256) f32 -> f16 pairs, layout [d][ks][k2][i][g] h2
//   k = ks*64 + k2*2 (+0/+1), gate g row = g*256+i
__global__ __launch_bounds__(256) void pack_whh_f16_k(const float* __restrict__ Whh,
                                                      h2_t* __restrict__ Wp) {
  const int idx = blockIdx.x * 256 + threadIdx.x;   // [0, 262144)
  const int g  = idx & 3;
  const int i  = (idx >> 2) & 255;
  const int k2 = (idx >> 10) & 31;
  const int ks = (idx >> 15) & 3;
  const int d  = idx >> 17;
  const int k  = ks * 64 + k2 * 2;
  const float* W = Whh + ((long)d * 1024 + g * 256 + i) * 256;
  h2_t v;
  v.x = (_Float16)W[k];
  v.y = (_Float16)W[k + 1];
  Wp[idx] = v;
}

// ---------------------------------------------------------------------------
// LSTM v2: one WG per (dir, batch-pair). 1024 threads = (ks 0..3, i 0..255).
// Each thread: 64-wide k-slice, 4 gates x 2 batch rows via v_dot2_f32_f16
// (weights reused across both rows from one 16B load). LDS reduce across ks,
// finalize by threads tid<512 which carry c in registers. x-gates for step
// t+1 prefetched into regs during the dot2 phase.
// ---------------------------------------------------------------------------
__global__ __launch_bounds__(1024) void lstm2_k(
    const float* __restrict__ Xg,   // (2, 8192, 1024)
    const uint4* __restrict__ Wp,   // (2,4,32,256) uint4 (= 4 gates h2)
    float* __restrict__ out)        // (128, 64, 512)
{
  const int bx = blockIdx.x;        // 0..63
  const int d  = bx >> 5;
  const int bp = bx & 31;
  const int tid = threadIdx.x;
  const int ks = tid >> 8;          // 0..3
  const int i  = tid & 255;

  __shared__ _Float16 hbuf[2][256];           // [row][i]
  __shared__ float part[4][2][4][256];        // [ks][row][g][i] = 32 KB

  if (tid < 512) hbuf[tid >> 8][tid & 255] = (_Float16)0.f;

  const int row  = tid >> 8;                  // finalize row (tid<512: 0/1)
  const int brow = bp * 2 + (row & 1);
  const float* Xd = Xg + (long)d * 8192 * 1024;

  float c = 0.f;
  float x0 = 0.f, x1 = 0.f, x2 = 0.f, x3 = 0.f;
  if (tid < 512) {
    const int t0 = d ? 127 : 0;
    const float* xr = Xd + ((long)(t0 * 64 + brow)) * 1024;
    x0 = xr[i]; x1 = xr[256 + i]; x2 = xr[512 + i]; x3 = xr[768 + i];
  }
  __syncthreads();

  const uint4* wbase = Wp + (((long)d * 4 + ks) * 32) * 256 + i;

  for (int step = 0; step < 128; ++step) {
    const int t = d ? (127 - step) : step;

    // prefetch next step's x-gates (overlaps dot2 phase)
    float xn0 = 0.f, xn1 = 0.f, xn2 = 0.f, xn3 = 0.f;
    if (tid < 512 && step + 1 < 128) {
      const int tn = d ? (126 - step) : (step + 1);
      const float* xr = Xd + ((long)(tn * 64 + brow)) * 1024;
      xn0 = xr[i]; xn1 = xr[256 + i]; xn2 = xr[512 + i]; xn3 = xr[768 + i];
    }

    // dot2 phase: 8 accumulators = 4 gates x 2 rows
    float a00 = 0.f, a01 = 0.f, a02 = 0.f, a03 = 0.f;
    float a10 = 0.f, a11 = 0.f, a12 = 0.f, a13 = 0.f;
    const h2_t* h0 = (const h2_t*)&hbuf[0][ks * 64];
    const h2_t* h1 = (const h2_t*)&hbuf[1][ks * 64];
#pragma unroll 8
    for (int k2 = 0; k2 < 32; ++k2) {
      uint4 w = wbase[k2 * 256];
      h2_t w0 = *(const h2_t*)&w.x;
      h2_t w1 = *(const h2_t*)&w.y;
      h2_t w2 = *(const h2_t*)&w.z;
      h2_t w3 = *(const h2_t*)&w.w;
      h2_t hv0 = h0[k2];
      h2_t hv1 = h1[k2];
      a00 = fdot2f(w0, hv0, a00); a01 = fdot2f(w1, hv0, a01);
      a02 = fdot2f(w2, hv0, a02); a03 = fdot2f(w3, hv0, a03);
      a10 = fdot2f(w0, hv1, a10); a11 = fdot2f(w1, hv1, a11);
      a12 = fdot2f(w2, hv1, a12); a13 = fdot2f(w3, hv1, a13);
    }
    part[ks][0][0][i] = a00; part[ks][0][1][i] = a01;
    part[ks][0][2][i] = a02; part[ks][0][3][i] = a03;
    part[ks][1][0][i] = a10; part[ks][1][1][i] = a11;
    part[ks][1][2][i] = a12; part[ks][1][3][i] = a13;
    __syncthreads();

    if (tid < 512) {
      float p0 = part[0][row][0][i] + part[1][row][0][i] + part[2][row][0][i] + part[3][row][0][i] + x0;
      float p1 = part[0][row][1][i] + part[1][row][1][i] + part[2][row][1][i] + part[3][row][1][i] + x1;
      float p2 = part[0][row][2][i] + part[1][row][2][i] + part[2][row][2][i] + part[3][row][2][i] + x2;
      float p3 = part[0][row][3][i] + part[1][row][3][i] + part[2][row][3][i] + part[3][row][3][i] + x3;
      const float ig = sigf(p0), fg = sigf(p1);
      const float gg = tanhf(p2), og = sigf(p3);
      c = fg * c + ig * gg;
      const float h = og * tanhf(c);
      hbuf[row][i] = (_Float16)h;
      out[((long)(t * 64 + brow)) * 512 + (d << 8) + i] = h;
      x0 = xn0; x1 = xn1; x2 = xn2; x3 = xn3;
    }
    __syncthreads();
  }
}

// ---------------------------------------------------------------------------
// Edge attention: softmax over source axis s (axis 0 of scale (L,B,L)),
// then window mask (1 / 1e-10) renormalization. scores: (B, t, s)
// ---------------------------------------------------------------------------
__global__ __launch_bounds__(128) void edge_softmax_k(const float* __restrict__ scale,
                                                      float* __restrict__ scores) {
  const int bx = blockIdx.x;            // b*128 + t
  const int b = bx >> 7, t = bx & 127;
  const int s = threadIdx.x;
  __shared__ float red[128];
  const float v = scale[((long)(s * 64 + b)) * 128 + t];
  red[s] = v; __syncthreads();
  for (int off = 64; off > 0; off >>= 1) { if (s < off) red[s] = fmaxf(red[s], red[s + off]); __syncthreads(); }
  const float m = red[0]; __syncthreads();
  const float e = expf(v - m);
  red[s] = e; __syncthreads();
  for (int off = 64; off > 0; off >>= 1) { if (s < off) red[s] += red[s + off]; __syncthreads(); }
  const float esum = red[0]; __syncthreads();
  const float alpha = e / esum;
  const int dd = s - t;
  const bool inwin = (dd <= 10) && (dd >= -10);
  const float masked = alpha * (inwin ? 1.0f : 1e-10f);
  red[s] = masked; __syncthreads();
  for (int off = 64; off > 0; off >>= 1) { if (s < off) red[s] += red[s + off]; __syncthreads(); }
  const float msum = red[0];
  scores[(long)bx * 128 + s] = inwin ? (masked / msum) : 0.f;
}

// x (conversation-major) from feats (time-major)
__global__ __launch_bounds__(256) void xbuf_k(const float* __restrict__ feats,
                                              float* __restrict__ xb) {
  const int n = blockIdx.x;
  const int b = n >> 7, t = n & 127;
  const int tid = threadIdx.x;
  const float* src = feats + (long)(t * 64 + b) * 512;
  float* dst = xb + (long)n * 512;
  dst[tid] = src[tid];
  dst[tid + 256] = src[tid + 256];
}

// W_rel basis combination, transposed for NN GEMM: Wrel2[f][r*256+o]
__global__ __launch_bounds__(256) void wrel_k(const float* __restrict__ basis,
                                              const float* __restrict__ comp,
                                              float* __restrict__ Wrel2) {
  const int f = blockIdx.x;     // 0..511
  const int o = threadIdx.x;    // 0..255
  __shared__ float cs[240];
  if (o < 240) cs[o] = comp[o];
  __syncthreads();
  float acc[8];
#pragma unroll
  for (int r = 0; r < 8; ++r) acc[r] = 0.f;
  for (int bb = 0; bb < 30; ++bb) {
    const float v = basis[((long)bb * 512 + f) * 256 + o];
#pragma unroll
    for (int r = 0; r < 8; ++r) acc[r] = fmaf(cs[r * 30 + bb], v, acc[r]);
  }
#pragma unroll
  for (int r = 0; r < 8; ++r) Wrel2[(long)f * 2048 + r * 256 + o] = acc[r];
}

// RGCN message gather
__global__ __launch_bounds__(256) void rgcn_gather_k(
    const float* __restrict__ xrel, const float* __restrict__ scores,
    const float* __restrict__ hroot, const int* __restrict__ spk,
    float* __restrict__ h)
{
  const int n = blockIdx.x;
  const int b = n >> 7, t = n & 127;
  const int o = threadIdx.x;
  const int lo = max(t - 10, 0), hi = min(t + 10, 127);
  const int cnt = hi - lo + 1;
  __shared__ int spks[21];
  __shared__ float wv[21];
  __shared__ int spkt_s;
  if (o < cnt) {
    spks[o] = spk[(lo + o) * 64 + b];
    wv[o] = scores[((long)(b * 128 + t)) * 128 + lo + o];
  }
  if (o == 0) spkt_s = spk[t * 64 + b];
  __syncthreads();
  const int spkt = spkt_s;
  float acc = hroot[(long)n * 256 + o];
  for (int q = 0; q < cnt; ++q) {
    const int s = lo + q;
    const int et = spkt * 4 + spks[q] * 2 + ((t < s) ? 0 : 1);
    acc = fmaf(xrel[(((long)(b * 128 + s)) * 8 + et) * 256 + o], wv[q], acc);
  }
  h[(long)n * 256 + o] = acc;
}

// GraphConv neighbor aggregation
__global__ __launch_bounds__(256) void agg_k(const float* __restrict__ h,
                                             float* __restrict__ agg) {
  const int n = blockIdx.x;
  const int b = n >> 7, t = n & 127;
  const int o = threadIdx.x;
  const int lo = max(t - 10, 0), hi = min(t + 10, 127);
  float acc = 0.f;
  for (int s = lo; s <= hi; ++s) acc += h[((long)(b * 128 + s)) * 256 + o];
  agg[(long)n * 256 + o] = acc;
}

// em = concat(x, h2)
__global__ __launch_bounds__(256) void em_k(const float* __restrict__ xb,
                                            const float* __restrict__ h2,
                                            float* __restrict__ em) {
  const int n = blockIdx.x;
  const int tid = threadIdx.x;
  em[(long)n * 768 + tid] = xb[(long)n * 512 + tid];
  em[(long)n * 768 + 256 + tid] = xb[(long)n * 512 + 256 + tid];
  em[(long)n * 768 + 512 + tid] = h2[(long)n * 256 + tid];
}

// Matching attention probs
__global__ __launch_bounds__(128) void match_softmax_k(float* __restrict__ logits,
                                                       const float* __restrict__ umask) {
  const int bx = blockIdx.x;           // b*128 + t
  const int b = bx >> 7;
  const int s = threadIdx.x;
  __shared__ float red[128];
  float* row = logits + (long)bx * 128;
  const float um = umask[b * 128 + s];
  const float v = tanhf(row[s] * um * um);
  red[s] = v; __syncthreads();
  for (int off = 64; off > 0; off >>= 1) { if (s < off) red[s] = fmaxf(red[s], red[s + off]); __syncthreads(); }
  const float m = red[0]; __syncthreads();
  const float e = expf(v - m);
  red[s] = e; __syncthreads();
  for (int off = 64; off > 0; off >>= 1) { if (s < off) red[s] += red[s + off]; __syncthreads(); }
  const float es = red[0]; __syncthreads();
  const float p = (e / es) * um;
  red[s] = p; __syncthreads();
  for (int off = 64; off > 0; off >>= 1) { if (s < off) red[s] += red[s + off]; __syncthreads(); }
  const float ps = red[0];
  row[s] = p / ps;
}

// Final: out = log_softmax(hidden @ Ws + bs)
__global__ __launch_bounds__(256) void final_k(const float* __restrict__ hidden,
                                               const float* __restrict__ Ws,
                                               const float* __restrict__ bs,
                                               float* __restrict__ out) {
  __shared__ float wsl[256 * 6];
  const int tid = threadIdx.x;
#pragma unroll
  for (int j = 0; j < 6; ++j) wsl[tid * 6 + j] = Ws[tid * 6 + j];
  __syncthreads();
  const int wave = tid >> 6, lane = tid & 63;
  const int n = blockIdx.x * 4 + wave;
  const float4 hv = *(const float4*)&hidden[(long)n * 256 + lane * 4];
  const float hvv[4] = {hv.x, hv.y, hv.z, hv.w};
  float a[6];
#pragma unroll
  for (int c = 0; c < 6; ++c) a[c] = 0.f;
#pragma unroll
  for (int j = 0; j < 4; ++j)
#pragma unroll
    for (int c = 0; c < 6; ++c)
      a[c] = fmaf(hvv[j], wsl[(lane * 4 + j) * 6 + c], a[c]);
#pragma unroll
  for (int off = 32; off > 0; off >>= 1)
#pragma unroll
    for (int c = 0; c < 6; ++c)
      a[c] += __shfl_xor(a[c], off, 64);
  if (lane == 0) {
    float v[6], m = -1e30f;
#pragma unroll
    for (int c = 0; c < 6; ++c) { v[c] = a[c] + bs[c]; m = fmaxf(m, v[c]); }
    float sum = 0.f;
#pragma unroll
    for (int c = 0; c < 6; ++c) sum += expf(v[c] - m);
    const float lse = m + logf(sum);
#pragma unroll
    for (int c = 0; c < 6; ++c) out[(long)n * 6 + c] = v[c] - lse;
  }
}

// ---------------------------------------------------------------------------
// Orchestration
// ---------------------------------------------------------------------------
extern "C" void kernel_launch(void* const* d_in, const int* in_sizes, int n_in,
                              void* d_out, int out_size, void* d_ws, size_t ws_size,
                              hipStream_t stream) {
  const float* U        = (const float*)d_in[0];
  const float* umask    = (const float*)d_in[1];
  const float* Wih0     = (const float*)d_in[2];
  const float* Whh0     = (const float*)d_in[3];
  const float* b0       = (const float*)d_in[4];
  const float* Wih1     = (const float*)d_in[5];
  const float* Whh1     = (const float*)d_in[6];
  const float* b1       = (const float*)d_in[7];
  const float* W_scalar = (const float*)d_in[8];
  const float* basis    = (const float*)d_in[9];
  const float* comp     = (const float*)d_in[10];
  const float* W_root   = (const float*)d_in[11];
  const float* b_rgcn   = (const float*)d_in[12];
  const float* gc_W1    = (const float*)d_in[13];
  const float* gc_W2    = (const float*)d_in[14];
  const float* gc_b     = (const float*)d_in[15];
  const float* Wm       = (const float*)d_in[16];
  const float* bm       = (const float*)d_in[17];
  const float* Wl       = (const float*)d_in[18];
  const float* bl       = (const float*)d_in[19];
  const float* Wsw      = (const float*)d_in[20];
  const float* bsw      = (const float*)d_in[21];
  const int*   speakers = (const int*)d_in[22];

  float* ws = (float*)d_ws;
  float* gates   = ws + 0L;          // 16,777,216
  float* feats   = ws + 16777216L;   //  4,194,304
  float* xbuf    = ws + 20971520L;   //  4,194,304
  float* feats0  = ws + 25165824L;   //  4,194,304
  float* scaleb  = ws + 29360128L;   //  1,048,576
  float* scoresb = ws + 30408704L;   //  1,048,576
  float* wrel2   = ws + 31457280L;   //  1,048,576
  float* hroot   = ws + 32505856L;   //  2,097,152
  h2_t*  wp0     = (h2_t*)(ws + 34603008L);   // 1 MB
  h2_t*  wp1     = wp0 + 262144L;             // 1 MB

  float* xrel    = gates;
  float* hb      = feats0;
  float* aggb    = feats0 + 2097152L;
  float* h2b     = hroot;
  float* emb     = gates;
  float* xtrb    = gates + 6291456L;
  float* logitsb = scaleb;
  float* attb    = feats;
  float* hiddenb = scaleb;

  // --- pack recurrent weights (f16 pairs, gate-interleaved) ---
  pack_whh_f16_k<<<1024, 256, 0, stream>>>(Whh0, wp0);
  pack_whh_f16_k<<<1024, 256, 0, stream>>>(Whh1, wp1);

  // --- layer 0 ---
  gemm_k<true, true, false, false><<<dim3(8, 64, 2), 256, 0, stream>>>(
      U, Wih0, b0, gates, 8192, 1024, 1024, 0L, 1048576L, 8388608L, 1024L);
  lstm2_k<<<64, 1024, 0, stream>>>(gates, (const uint4*)wp0, feats0);

  // --- layer 1 ---
  gemm_k<true, true, false, false><<<dim3(8, 64, 2), 256, 0, stream>>>(
      feats0, Wih1, b1, gates, 8192, 1024, 512, 0L, 524288L, 8388608L, 1024L);
  lstm2_k<<<64, 1024, 0, stream>>>(gates, (const uint4*)wp1, feats);

  // --- edge attention scores ---
  gemm_k<false, false, false, false><<<dim3(1, 64, 1), 256, 0, stream>>>(
      feats, W_scalar, nullptr, scaleb, 8192, 128, 512, 0L, 0L, 0L, 0L);
  edge_softmax_k<<<8192, 128, 0, stream>>>(scaleb, scoresb);

  // --- node features (b-major) + RGCN ---
  xbuf_k<<<8192, 256, 0, stream>>>(feats, xbuf);
  wrel_k<<<512, 256, 0, stream>>>(basis, comp, wrel2);
  gemm_k<false, true, false, false><<<dim3(2, 64, 1), 256, 0, stream>>>(
      xbuf, W_root, b_rgcn, hroot, 8192, 256, 512, 0L, 0L, 0L, 0L);
  gemm_k<false, false, false, false><<<dim3(16, 64, 1), 256, 0, stream>>>(
      xbuf, wrel2, nullptr, xrel, 8192, 2048, 512, 0L, 0L, 0L, 0L);
  rgcn_gather_k<<<8192, 256, 0, stream>>>(xrel, scoresb, hroot, speakers, hb);

  // --- GraphConv ---
  agg_k<<<8192, 256, 0, stream>>>(hb, aggb);
  gemm_k<false, true, false, false><<<dim3(2, 64, 1), 256, 0, stream>>>(
      hb, gc_W1, gc_b, h2b, 8192, 256, 256, 0L, 0L, 0L, 0L);
  gemm_k<false, false, true, false><<<dim3(2, 64, 1), 256, 0, stream>>>(
      aggb, gc_W2, nullptr, h2b, 8192, 256, 256, 0L, 0L, 0L, 0L);

  // --- matching attention ---
  em_k<<<8192, 256, 0, stream>>>(xbuf, h2b, emb);
  gemm_k<false, true, false, false><<<dim3(6, 64, 1), 256, 0, stream>>>(
      emb, Wm, bm, xtrb, 8192, 768, 768, 0L, 0L, 0L, 0L);
  gemm_k<true, false, false, false><<<dim3(1, 1, 64), 256, 0, stream>>>(
      xtrb, emb, nullptr, logitsb, 128, 128, 768, 98304L, 98304L, 16384L, 0L);
  match_softmax_k<<<8192, 128, 0, stream>>>(logitsb, umask);
  gemm_k<false, false, false, false><<<dim3(6, 1, 64), 256, 0, stream>>>(
      logitsb, emb, nullptr, attb, 128, 768, 128, 16384L, 98304L, 98304L, 0L);

  // --- classifier ---
  gemm_k<false, true, false, true><<<dim3(2, 64, 1), 256, 0, stream>>>(
      attb, Wl, bl, hiddenb, 8192, 256, 768, 0L, 0L, 0L, 0L);
  final_k<<<2048, 256, 0, stream>>>(hiddenb, Wsw, bsw, (float*)d_out);
}

// Round 3
// 1514.334 us; speedup vs baseline: 2.3330x; 1.8168x over previous
//
#include <hip/hip_runtime.h>
#include <cstdint>

// Model dims (fixed): L=128, B=64, DM=1024, H=256, F=512, HID=256, MEM=768,
// N=B*L=8192, NC=6, R=8, NB=30, WIN=10

typedef __attribute__((ext_vector_type(8))) short bf16x8;
typedef __attribute__((ext_vector_type(4))) float f32x4;

// ---------------------------------------------------------------------------
// Generic fp32 GEMM (kept for mid-size ops): C = A(MxK)*B + bias, NN or NT.
// ---------------------------------------------------------------------------
#define BMg 128
#define BNg 128
#define BKg 16

template<bool TRANSB, bool HASBIAS, bool ACCUM, bool RELU>
__global__ __launch_bounds__(256) void gemm_k(
    const float* __restrict__ A, const float* __restrict__ Bm,
    const float* __restrict__ bias, float* __restrict__ C,
    int M, int Nd, int K, long sA, long sB, long sC, long sBias)
{
  const int bz = blockIdx.z;
  A += (long)bz * sA;
  Bm += (long)bz * sB;
  C += (long)bz * sC;
  if (HASBIAS) bias += (long)bz * sBias;

  const int bn = blockIdx.x * BNg;
  const int bm = blockIdx.y * BMg;

  __shared__ float As[BKg][BMg + 4];
  __shared__ float Bs[BKg][BNg + 4];

  const int tid = threadIdx.x;
  const int tm = (tid >> 4) << 3;
  const int tn = (tid & 15) << 3;

  float acc[8][8];
#pragma unroll
  for (int r = 0; r < 8; ++r)
#pragma unroll
    for (int c = 0; c < 8; ++c) acc[r][c] = 0.f;

  const int lr = tid >> 1;
  const int lk = (tid & 1) * 8;
  const int bkr = tid >> 4;
  const int bnc = (tid & 15) * 8;

  for (int k0 = 0; k0 < K; k0 += BKg) {
    {
      const float* ap = A + (long)(bm + lr) * K + k0 + lk;
      float4 a0 = *(const float4*)ap;
      float4 a1 = *(const float4*)(ap + 4);
      As[lk + 0][lr] = a0.x; As[lk + 1][lr] = a0.y; As[lk + 2][lr] = a0.z; As[lk + 3][lr] = a0.w;
      As[lk + 4][lr] = a1.x; As[lk + 5][lr] = a1.y; As[lk + 6][lr] = a1.z; As[lk + 7][lr] = a1.w;
    }
    if (TRANSB) {
      const float* bp = Bm + (long)(bn + lr) * K + k0 + lk;
      float4 b0 = *(const float4*)bp;
      float4 b1 = *(const float4*)(bp + 4);
      Bs[lk + 0][lr] = b0.x; Bs[lk + 1][lr] = b0.y; Bs[lk + 2][lr] = b0.z; Bs[lk + 3][lr] = b0.w;
      Bs[lk + 4][lr] = b1.x; Bs[lk + 5][lr] = b1.y; Bs[lk + 6][lr] = b1.z; Bs[lk + 7][lr] = b1.w;
    } else {
      const float* bp = Bm + (long)(k0 + bkr) * Nd + bn + bnc;
      float4 b0 = *(const float4*)bp;
      float4 b1 = *(const float4*)(bp + 4);
      *(float4*)&Bs[bkr][bnc] = b0;
      *(float4*)&Bs[bkr][bnc + 4] = b1;
    }
    __syncthreads();
#pragma unroll
    for (int kk = 0; kk < BKg; ++kk) {
      float4 a0 = *(const float4*)&As[kk][tm];
      float4 a1 = *(const float4*)&As[kk][tm + 4];
      float4 b0 = *(const float4*)&Bs[kk][tn];
      float4 b1 = *(const float4*)&Bs[kk][tn + 4];
      float av[8] = {a0.x, a0.y, a0.z, a0.w, a1.x, a1.y, a1.z, a1.w};
      float bv[8] = {b0.x, b0.y, b0.z, b0.w, b1.x, b1.y, b1.z, b1.w};
#pragma unroll
      for (int r = 0; r < 8; ++r)
#pragma unroll
        for (int c = 0; c < 8; ++c)
          acc[r][c] = fmaf(av[r], bv[c], acc[r][c]);
    }
    __syncthreads();
  }

#pragma unroll
  for (int r = 0; r < 8; ++r) {
    float* cp = C + (long)(bm + tm + r) * Nd + bn + tn;
#pragma unroll
    for (int c = 0; c < 8; ++c) {
      float v = acc[r][c];
      if (HASBIAS) v += bias[bn + tn + c];
      if (ACCUM) v += cp[c];
      if (RELU) v = fmaxf(v, 0.f);
      cp[c] = v;
    }
  }
}

// ---------------------------------------------------------------------------
// bf16 NT MFMA GEMM: C(MxN) f32 = A(MxK)bf16 @ Bt(NxK)bf16^T (+bias)
// 128x128x32 tile, 4 waves (2x2), 16x16x32 MFMA, 4x4 frags/wave.
// ---------------------------------------------------------------------------
template<bool HASBIAS, bool RELU>
__global__ __launch_bounds__(256) void gemm_bf16_nt(
    const ushort* __restrict__ A, const ushort* __restrict__ Bt,
    const float* __restrict__ bias, float* __restrict__ C,
    int M, int N, int K, long sB, long sC, long sBias)
{
  const int bz = blockIdx.z;
  Bt += (long)bz * sB; C += (long)bz * sC;
  if (HASBIAS) bias += (long)bz * sBias;
  const int bn = blockIdx.x * 128, bm = blockIdx.y * 128;

  __shared__ ushort As[128][40];   // +8 pad: 2-way-max bank aliasing
  __shared__ ushort Bs[128][40];

  const int tid = threadIdx.x;
  const int wave = tid >> 6, lane = tid & 63;
  const int wm = (wave >> 1) * 64, wn = (wave & 1) * 64;
  const int fr = lane & 15;             // frag row (A) / col (B)
  const int fk = (lane >> 4) * 8;       // k-offset within frag

  f32x4 acc[4][4];
#pragma unroll
  for (int i = 0; i < 4; ++i)
#pragma unroll
    for (int j = 0; j < 4; ++j) acc[i][j] = (f32x4){0.f, 0.f, 0.f, 0.f};

  const int sr = tid >> 1;              // staging row 0..127
  const int sq = (tid & 1) * 16;        // bf16 element offset 0/16

  for (int k0 = 0; k0 < K; k0 += 32) {
    const uint4* ga = (const uint4*)(A + (long)(bm + sr) * K + k0 + sq);
    uint4 av0 = ga[0], av1 = ga[1];
    const uint4* gb = (const uint4*)(Bt + (long)(bn + sr) * K + k0 + sq);
    uint4 bv0 = gb[0], bv1 = gb[1];
    *(uint4*)&As[sr][sq] = av0;
    *(uint4*)&As[sr][sq + 8] = av1;
    *(uint4*)&Bs[sr][sq] = bv0;
    *(uint4*)&Bs[sr][sq + 8] = bv1;
    __syncthreads();

    bf16x8 af[4], bfr[4];
#pragma unroll
    for (int f = 0; f < 4; ++f) {
      af[f]  = *(const bf16x8*)&As[wm + f * 16 + fr][fk];
      bfr[f] = *(const bf16x8*)&Bs[wn + f * 16 + fr][fk];
    }
#pragma unroll
    for (int mf = 0; mf < 4; ++mf)
#pragma unroll
      for (int nf = 0; nf < 4; ++nf)
        acc[mf][nf] = __builtin_amdgcn_mfma_f32_16x16x32_bf16(
            af[mf], bfr[nf], acc[mf][nf], 0, 0, 0);
    __syncthreads();
  }

  float bv[4];
#pragma unroll
  for (int nf = 0; nf < 4; ++nf)
    bv[nf] = HASBIAS ? bias[bn + wn + nf * 16 + fr] : 0.f;

  const int crow0 = (lane >> 4) * 4;
#pragma unroll
  for (int mf = 0; mf < 4; ++mf)
#pragma unroll
    for (int r = 0; r < 4; ++r) {
      float* cp = C + (long)(bm + wm + mf * 16 + crow0 + r) * N + bn + wn;
#pragma unroll
      for (int nf = 0; nf < 4; ++nf) {
        float v = acc[mf][nf][r] + bv[nf];
        if (RELU) v = fmaxf(v, 0.f);
        cp[nf * 16 + fr] = v;
      }
    }
}

// ---------------------------------------------------------------------------
// helpers
// ---------------------------------------------------------------------------
__device__ __forceinline__ unsigned short f2bf(float f) {
  unsigned u = __float_as_uint(f);
  u += 0x7fffu + ((u >> 16) & 1u);
  return (unsigned short)(u >> 16);
}
__device__ __forceinline__ float sigf(float x) { return 1.f / (1.f + expf(-x)); }

__device__ __forceinline__ int sdot4_(uint a, uint b, int c) {
#if __has_builtin(__builtin_amdgcn_sdot4)
  return __builtin_amdgcn_sdot4((int)a, (int)b, c, false);
#else
  int r = c;
  r += ((int)(a << 24) >> 24) * ((int)(b << 24) >> 24);
  r += ((int)(a << 16) >> 24) * ((int)(b << 16) >> 24);
  r += ((int)(a << 8)  >> 24) * ((int)(b << 8)  >> 24);
  r += ((int)a >> 24)         * ((int)b >> 24);
  return r;
#endif
}

// f32 -> bf16 convert (n multiple of 1024)
__global__ __launch_bounds__(256) void cvt_bf16_k(const float* __restrict__ src,
                                                  ushort* __restrict__ dst) {
  const long i = ((long)blockIdx.x * 256 + threadIdx.x) * 4;
  float4 v = *(const float4*)(src + i);
  ushort4 o;
  o.x = f2bf(v.x); o.y = f2bf(v.y); o.z = f2bf(v.z); o.w = f2bf(v.w);
  *(ushort4*)(dst + i) = o;
}

// Whh (2,1024,256) f32 -> int8 [d][k4][gi] dwords + per-row scale [d][gi]
__global__ __launch_bounds__(256) void pack_whh_i8_k(const float* __restrict__ Whh,
                                                     uint* __restrict__ Wq,
                                                     float* __restrict__ fscale) {
  const int wid = (blockIdx.x * 256 + threadIdx.x) >> 6;  // 0..2047
  const int lane = threadIdx.x & 63;
  const int d = wid >> 10, gi = wid & 1023;
  const float* row = Whh + ((long)d * 1024 + gi) * 256 + lane * 4;
  float v0 = row[0], v1 = row[1], v2 = row[2], v3 = row[3];
  float am = fmaxf(fmaxf(fabsf(v0), fabsf(v1)), fmaxf(fabsf(v2), fabsf(v3)));
#pragma unroll
  for (int off = 32; off > 0; off >>= 1) am = fmaxf(am, __shfl_xor(am, off, 64));
  am = fmaxf(am, 1e-12f);
  const float inv = 127.f / am;
  int q0 = __float2int_rn(v0 * inv), q1 = __float2int_rn(v1 * inv);
  int q2 = __float2int_rn(v2 * inv), q3 = __float2int_rn(v3 * inv);
  uint w = (uint)(q0 & 255) | ((uint)(q1 & 255) << 8) |
           ((uint)(q2 & 255) << 16) | ((uint)(q3 & 255) << 24);
  Wq[((long)d * 64 + lane) * 1024 + gi] = w;
  if (lane == 0) fscale[d * 1024 + gi] = am / 127.f;
}

// ---------------------------------------------------------------------------
// LSTM v3: int8 weights (112KB LDS-resident + 144KB/step streamed), int8 h,
// sdot4 accumulation. 128 WGs = (dir, batch-row); 1024 thr = (gate, out-i).
// ---------------------------------------------------------------------------
#define WLDS 28   // k4 slices resident in LDS (of 64)

__global__ __launch_bounds__(1024) void lstm3_k(
    const float* __restrict__ Xg,    // (2, 8192, 1024) x-part gate preacts
    const uint* __restrict__ Wq,     // (2, 64, 1024) int8-packed dwords
    const float* __restrict__ fscale,// (2, 1024)
    float* __restrict__ out)         // (128, 64, 512)
{
  const int bx = blockIdx.x;         // d*64 + b
  const int d = bx >> 6, b = bx & 63;
  const int tid = threadIdx.x;       // gi = g*256+i

  __shared__ uint wlds[WLDS * 1024]; // 112 KB
  __shared__ float preactF[1024];    // 4 KB
  __shared__ uint hq[2][64];         // 512 B (int8 h, double-buffered)

  const uint* wrow = Wq + (long)d * 65536 + tid;
#pragma unroll
  for (int k4 = 0; k4 < WLDS; ++k4) wlds[k4 * 1024 + tid] = wrow[k4 * 1024];
  if (tid < 128) ((uint*)hq)[tid] = 0u;

  const float fsc = fscale[d * 1024 + tid] * (1.0f / 127.0f);
  const float* Xd = Xg + (long)d * 8192 * 1024;
  const uint* wstr = wrow + WLDS * 1024;

  float c = 0.f;
  float x0 = 0.f, x1 = 0.f, x2 = 0.f, x3 = 0.f;
  if (tid < 256) {
    const float* xr = Xd + ((long)((d ? 127 : 0) * 64 + b)) * 1024;
    x0 = xr[tid]; x1 = xr[tid + 256]; x2 = xr[tid + 512]; x3 = xr[tid + 768];
  }
  __syncthreads();

  int cur = 0;
  for (int step = 0; step < 128; ++step) {
    const int t = d ? 127 - step : step;

    // streamed weight slice (issued early; 36 dwords in flight)
    uint wg_[64 - WLDS];
#pragma unroll
    for (int k4 = 0; k4 < 64 - WLDS; ++k4) wg_[k4] = wstr[k4 * 1024];

    // prefetch next-step x gates
    float n0 = 0.f, n1 = 0.f, n2 = 0.f, n3 = 0.f;
    if (tid < 256 && step + 1 < 128) {
      const float* xr = Xd + ((long)((d ? 126 - step : step + 1) * 64 + b)) * 1024;
      n0 = xr[tid]; n1 = xr[tid + 256]; n2 = xr[tid + 512]; n3 = xr[tid + 768];
    }

    int acc = 0;
    const uint* hrow = hq[cur];
#pragma unroll
    for (int k4 = 0; k4 < WLDS; ++k4)
      acc = sdot4_(wlds[k4 * 1024 + tid], hrow[k4], acc);
#pragma unroll
    for (int k4 = 0; k4 < 64 - WLDS; ++k4)
      acc = sdot4_(wg_[k4], hrow[WLDS + k4], acc);

    preactF[tid] = (float)acc * fsc;
    __syncthreads();

    if (tid < 256) {
      float p0 = x0 + preactF[tid];
      float p1 = x1 + preactF[tid + 256];
      float p2 = x2 + preactF[tid + 512];
      float p3 = x3 + preactF[tid + 768];
      const float ig = sigf(p0), fg = sigf(p1);
      const float gg = tanhf(p2), og = sigf(p3);
      c = fg * c + ig * gg;
      const float h = og * tanhf(c);
      out[((long)(t * 64 + b)) * 512 + (d << 8) + tid] = h;
      ((char*)hq[cur ^ 1])[tid] = (char)__float2int_rn(h * 127.f);
      x0 = n0; x1 = n1; x2 = n2; x3 = n3;
    }
    __syncthreads();
    cur ^= 1;
  }
}

// ---------------------------------------------------------------------------
// Edge attention softmax + window renorm. scores: (B, t, s)
// ---------------------------------------------------------------------------
__global__ __launch_bounds__(128) void edge_softmax_k(const float* __restrict__ scale,
                                                      float* __restrict__ scores) {
  const int bx = blockIdx.x;            // b*128 + t
  const int b = bx >> 7, t = bx & 127;
  const int s = threadIdx.x;
  __shared__ float red[128];
  const float v = scale[((long)(s * 64 + b)) * 128 + t];
  red[s] = v; __syncthreads();
  for (int off = 64; off > 0; off >>= 1) { if (s < off) red[s] = fmaxf(red[s], red[s + off]); __syncthreads(); }
  const float m = red[0]; __syncthreads();
  const float e = expf(v - m);
  red[s] = e; __syncthreads();
  for (int off = 64; off > 0; off >>= 1) { if (s < off) red[s] += red[s + off]; __syncthreads(); }
  const float esum = red[0]; __syncthreads();
  const float alpha = e / esum;
  const int dd = s - t;
  const bool inwin = (dd <= 10) && (dd >= -10);
  const float masked = alpha * (inwin ? 1.0f : 1e-10f);
  red[s] = masked; __syncthreads();
  for (int off = 64; off > 0; off >>= 1) { if (s < off) red[s] += red[s + off]; __syncthreads(); }
  const float msum = red[0];
  scores[(long)bx * 128 + s] = inwin ? (masked / msum) : 0.f;
}

__global__ __launch_bounds__(256) void xbuf_k(const float* __restrict__ feats,
                                              float* __restrict__ xb) {
  const int n = blockIdx.x;
  const int b = n >> 7, t = n & 127;
  const int tid = threadIdx.x;
  const float* src = feats + (long)(t * 64 + b) * 512;
  float* dst = xb + (long)n * 512;
  dst[tid] = src[tid];
  dst[tid + 256] = src[tid + 256];
}

__global__ __launch_bounds__(256) void wrel_k(const float* __restrict__ basis,
                                              const float* __restrict__ comp,
                                              float* __restrict__ Wrel2) {
  const int f = blockIdx.x;     // 0..511
  const int o = threadIdx.x;    // 0..255
  __shared__ float cs[240];
  if (o < 240) cs[o] = comp[o];
  __syncthreads();
  float acc[8];
#pragma unroll
  for (int r = 0; r < 8; ++r) acc[r] = 0.f;
  for (int bb = 0; bb < 30; ++bb) {
    const float v = basis[((long)bb * 512 + f) * 256 + o];
#pragma unroll
    for (int r = 0; r < 8; ++r) acc[r] = fmaf(cs[r * 30 + bb], v, acc[r]);
  }
#pragma unroll
  for (int r = 0; r < 8; ++r) Wrel2[(long)f * 2048 + r * 256 + o] = acc[r];
}

__global__ __launch_bounds__(256) void rgcn_gather_k(
    const float* __restrict__ xrel, const float* __restrict__ scores,
    const float* __restrict__ hroot, const int* __restrict__ spk,
    float* __restrict__ h)
{
  const int n = blockIdx.x;
  const int b = n >> 7, t = n & 127;
  const int o = threadIdx.x;
  const int lo = max(t - 10, 0), hi = min(t + 10, 127);
  const int cnt = hi - lo + 1;
  __shared__ int spks[21];
  __shared__ float wv[21];
  __shared__ int spkt_s;
  if (o < cnt) {
    spks[o] = spk[(lo + o) * 64 + b];
    wv[o] = scores[((long)(b * 128 + t)) * 128 + lo + o];
  }
  if (o == 0) spkt_s = spk[t * 64 + b];
  __syncthreads();
  const int spkt = spkt_s;
  float acc = hroot[(long)n * 256 + o];
  for (int q = 0; q < cnt; ++q) {
    const int s = lo + q;
    const int et = spkt * 4 + spks[q] * 2 + ((t < s) ? 0 : 1);
    acc = fmaf(xrel[(((long)(b * 128 + s)) * 8 + et) * 256 + o], wv[q], acc);
  }
  h[(long)n * 256 + o] = acc;
}

__global__ __launch_bounds__(256) void agg_k(const float* __restrict__ h,
                                             float* __restrict__ agg) {
  const int n = blockIdx.x;
  const int b = n >> 7, t = n & 127;
  const int o = threadIdx.x;
  const int lo = max(t - 10, 0), hi = min(t + 10, 127);
  float acc = 0.f;
  for (int s = lo; s <= hi; ++s) acc += h[((long)(b * 128 + s)) * 256 + o];
  agg[(long)n * 256 + o] = acc;
}

__global__ __launch_bounds__(256) void em_k(const float* __restrict__ xb,
                                            const float* __restrict__ h2,
                                            float* __restrict__ em) {
  const int n = blockIdx.x;
  const int tid = threadIdx.x;
  em[(long)n * 768 + tid] = xb[(long)n * 512 + tid];
  em[(long)n * 768 + 256 + tid] = xb[(long)n * 512 + 256 + tid];
  em[(long)n * 768 + 512 + tid] = h2[(long)n * 256 + tid];
}

__global__ __launch_bounds__(128) void match_softmax_k(float* __restrict__ logits,
                                                       const float* __restrict__ umask) {
  const int bx = blockIdx.x;           // b*128 + t
  const int b = bx >> 7;
  const int s = threadIdx.x;
  __shared__ float red[128];
  float* row = logits + (long)bx * 128;
  const float um = umask[b * 128 + s];
  const float v = tanhf(row[s] * um * um);
  red[s] = v; __syncthreads();
  for (int off = 64; off > 0; off >>= 1) { if (s < off) red[s] = fmaxf(red[s], red[s + off]); __syncthreads(); }
  const float m = red[0]; __syncthreads();
  const float e = expf(v - m);
  red[s] = e; __syncthreads();
  for (int off = 64; off > 0; off >>= 1) { if (s < off) red[s] += red[s + off]; __syncthreads(); }
  const float es = red[0]; __syncthreads();
  const float p = (e / es) * um;
  red[s] = p; __syncthreads();
  for (int off = 64; off > 0; off >>= 1) { if (s < off) red[s] += red[s + off]; __syncthreads(); }
  const float ps = red[0];
  row[s] = p / ps;
}

__global__ __launch_bounds__(256) void final_k(const float* __restrict__ hidden,
                                               const float* __restrict__ Ws,
                                               const float* __restrict__ bs,
                                               float* __restrict__ out) {
  __shared__ float wsl[256 * 6];
  const int tid = threadIdx.x;
#pragma unroll
  for (int j = 0; j < 6; ++j) wsl[tid * 6 + j] = Ws[tid * 6 + j];
  __syncthreads();
  const int wave = tid >> 6, lane = tid & 63;
  const int n = blockIdx.x * 4 + wave;
  const float4 hv = *(const float4*)&hidden[(long)n * 256 + lane * 4];
  const float hvv[4] = {hv.x, hv.y, hv.z, hv.w};
  float a[6];
#pragma unroll
  for (int c = 0; c < 6; ++c) a[c] = 0.f;
#pragma unroll
  for (int j = 0; j < 4; ++j)
#pragma unroll
    for (int c = 0; c < 6; ++c)
      a[c] = fmaf(hvv[j], wsl[(lane * 4 + j) * 6 + c], a[c]);
#pragma unroll
  for (int off = 32; off > 0; off >>= 1)
#pragma unroll
    for (int c = 0; c < 6; ++c)
      a[c] += __shfl_xor(a[c], off, 64);
  if (lane == 0) {
    float v[6], m = -1e30f;
#pragma unroll
    for (int c = 0; c < 6; ++c) { v[c] = a[c] + bs[c]; m = fmaxf(m, v[c]); }
    float sum = 0.f;
#pragma unroll
    for (int c = 0; c < 6; ++c) sum += expf(v[c] - m);
    const float lse = m + logf(sum);
#pragma unroll
    for (int c = 0; c < 6; ++c) out[(long)n * 6 + c] = v[c] - lse;
  }
}

// ---------------------------------------------------------------------------
// Orchestration
// ---------------------------------------------------------------------------
extern "C" void kernel_launch(void* const* d_in, const int* in_sizes, int n_in,
                              void* d_out, int out_size, void* d_ws, size_t ws_size,
                              hipStream_t stream) {
  const float* U        = (const float*)d_in[0];
  const float* umask    = (const float*)d_in[1];
  const float* Wih0     = (const float*)d_in[2];
  const float* Whh0     = (const float*)d_in[3];
  const float* b0       = (const float*)d_in[4];
  const float* Wih1     = (const float*)d_in[5];
  const float* Whh1     = (const float*)d_in[6];
  const float* b1       = (const float*)d_in[7];
  const float* W_scalar = (const float*)d_in[8];
  const float* basis    = (const float*)d_in[9];
  const float* comp     = (const float*)d_in[10];
  const float* W_root   = (const float*)d_in[11];
  const float* b_rgcn   = (const float*)d_in[12];
  const float* gc_W1    = (const float*)d_in[13];
  const float* gc_W2    = (const float*)d_in[14];
  const float* gc_b     = (const float*)d_in[15];
  const float* Wm       = (const float*)d_in[16];
  const float* bm       = (const float*)d_in[17];
  const float* Wl       = (const float*)d_in[18];
  const float* bl       = (const float*)d_in[19];
  const float* Wsw      = (const float*)d_in[20];
  const float* bsw      = (const float*)d_in[21];
  const int*   speakers = (const int*)d_in[22];

  float* ws = (float*)d_ws;
  float* gates   = ws + 0L;          // 16,777,216 f  X gates -> xrel -> em/xtr
  float* feats   = ws + 16777216L;   //  4,194,304 f  (early: Wih bf16) -> L1 out -> att
  float* xbuf    = ws + 20971520L;   //  4,194,304 f  (early: U bf16) -> x b-major
  float* feats0  = ws + 25165824L;   //  4,194,304 f  L0 out -> h + agg
  float* scaleb  = ws + 29360128L;   //  1,048,576 f  scale -> logits -> hidden
  float* scoresb = ws + 30408704L;   //  1,048,576 f
  float* wrel2   = ws + 31457280L;   //  1,048,576 f
  float* hroot   = ws + 32505856L;   //  2,097,152 f  (early: feats0 bf16) -> hroot -> h2
  uint*  wq      = (uint*)(ws + 34603008L);   // 2 layers x 131,072 dwords
  float* fsc     = ws + 34603008L + 262144L;  // 2 layers x 2048 f

  // bf16 staging (region reuse)
  ushort* ubf    = (ushort*)xbuf;               // 8,388,608 us (16.8 MB)
  ushort* wih0bf = (ushort*)feats;              // 2,097,152 us
  ushort* wih1bf = (ushort*)(feats + 1048576L); // 1,048,576 us
  ushort* f0bf   = (ushort*)hroot;              // 4,194,304 us

  float* xrel    = gates;
  float* hb      = feats0;
  float* aggb    = feats0 + 2097152L;
  float* h2b     = hroot;
  float* emb     = gates;
  float* xtrb    = gates + 6291456L;
  float* logitsb = scaleb;
  float* attb    = feats;
  float* hiddenb = scaleb;

  // --- weight prep ---
  pack_whh_i8_k<<<512, 256, 0, stream>>>(Whh0, wq, fsc);
  pack_whh_i8_k<<<512, 256, 0, stream>>>(Whh1, wq + 131072, fsc + 2048);
  cvt_bf16_k<<<8192, 256, 0, stream>>>(U, ubf);
  cvt_bf16_k<<<2048, 256, 0, stream>>>(Wih0, wih0bf);
  cvt_bf16_k<<<1024, 256, 0, stream>>>(Wih1, wih1bf);

  // --- layer 0 ---
  gemm_bf16_nt<true, false><<<dim3(8, 64, 2), 256, 0, stream>>>(
      ubf, wih0bf, b0, gates, 8192, 1024, 1024, 1048576L, 8388608L, 1024L);
  lstm3_k<<<128, 1024, 0, stream>>>(gates, wq, fsc, feats0);

  // --- layer 1 ---
  cvt_bf16_k<<<4096, 256, 0, stream>>>(feats0, f0bf);
  gemm_bf16_nt<true, false><<<dim3(8, 64, 2), 256, 0, stream>>>(
      f0bf, wih1bf, b1, gates, 8192, 1024, 512, 524288L, 8388608L, 1024L);
  lstm3_k<<<128, 1024, 0, stream>>>(gates, wq + 131072, fsc + 2048, feats);

  // --- edge attention scores ---
  gemm_k<false, false, false, false><<<dim3(1, 64, 1), 256, 0, stream>>>(
      feats, W_scalar, nullptr, scaleb, 8192, 128, 512, 0L, 0L, 0L, 0L);
  edge_softmax_k<<<8192, 128, 0, stream>>>(scaleb, scoresb);

  // --- node features (b-major) + RGCN ---
  xbuf_k<<<8192, 256, 0, stream>>>(feats, xbuf);
  wrel_k<<<512, 256, 0, stream>>>(basis, comp, wrel2);
  gemm_k<false, true, false, false><<<dim3(2, 64, 1), 256, 0, stream>>>(
      xbuf, W_root, b_rgcn, hroot, 8192, 256, 512, 0L, 0L, 0L, 0L);
  gemm_k<false, false, false, false><<<dim3(16, 64, 1), 256, 0, stream>>>(
      xbuf, wrel2, nullptr, xrel, 8192, 2048, 512, 0L, 0L, 0L, 0L);
  rgcn_gather_k<<<8192, 256, 0, stream>>>(xrel, scoresb, hroot, speakers, hb);

  // --- GraphConv ---
  agg_k<<<8192, 256, 0, stream>>>(hb, aggb);
  gemm_k<false, true, false, false><<<dim3(2, 64, 1), 256, 0, stream>>>(
      hb, gc_W1, gc_b, h2b, 8192, 256, 256, 0L, 0L, 0L, 0L);
  gemm_k<false, false, true, false><<<dim3(2, 64, 1), 256, 0, stream>>>(
      aggb, gc_W2, nullptr, h2b, 8192, 256, 256, 0L, 0L, 0L, 0L);

  // --- matching attention ---
  em_k<<<8192, 256, 0, stream>>>(xbuf, h2b, emb);
  gemm_k<false, true, false, false><<<dim3(6, 64, 1), 256, 0, stream>>>(
      emb, Wm, bm, xtrb, 8192, 768, 768, 0L, 0L, 0L, 0L);
  gemm_k<true, false, false, false><<<dim3(1, 1, 64), 256, 0, stream>>>(
      xtrb, emb, nullptr, logitsb, 128, 128, 768, 98304L, 98304L, 16384L, 0L);
  match_softmax_k<<<8192, 128, 0, stream>>>(logitsb, umask);
  gemm_k<false, false, false, false><<<dim3(6, 1, 64), 256, 0, stream>>>(
      logitsb, emb, nullptr, attb, 128, 768, 128, 16384L, 98304L, 98304L, 0L);

  // --- classifier ---
  gemm_k<false, true, false, true><<<dim3(2, 64, 1), 256, 0, stream>>>(
      attb, Wl, bl, hiddenb, 8192, 256, 768, 0L, 0L, 0L, 0L);
  final_k<<<2048, 256, 0, stream>>>(hiddenb, Wsw, bsw, (float*)d_out);
}

// Round 5
// 896.301 us; speedup vs baseline: 3.9417x; 1.6895x over previous
//
#include <hip/hip_runtime.h>
#include <cstdint>

// Model dims (fixed): L=128, B=64, DM=1024, H=256, F=512, HID=256, MEM=768,
// N=B*L=8192, NC=6, R=8, NB=30, WIN=10

typedef __attribute__((ext_vector_type(8))) short bf16x8;
typedef __attribute__((ext_vector_type(4))) float f32x4;

// ---------------------------------------------------------------------------
// Generic fp32 GEMM (small/batched ops): C = A(MxK)*B + bias, NN or NT.
// ---------------------------------------------------------------------------
#define BMg 128
#define BNg 128
#define BKg 16

template<bool TRANSB, bool HASBIAS, bool ACCUM, bool RELU>
__global__ __launch_bounds__(256) void gemm_k(
    const float* __restrict__ A, const float* __restrict__ Bm,
    const float* __restrict__ bias, float* __restrict__ C,
    int M, int Nd, int K, long sA, long sB, long sC, long sBias)
{
  const int bz = blockIdx.z;
  A += (long)bz * sA;
  Bm += (long)bz * sB;
  C += (long)bz * sC;
  if (HASBIAS) bias += (long)bz * sBias;

  const int bn = blockIdx.x * BNg;
  const int bm = blockIdx.y * BMg;

  __shared__ float As[BKg][BMg + 4];
  __shared__ float Bs[BKg][BNg + 4];

  const int tid = threadIdx.x;
  const int tm = (tid >> 4) << 3;
  const int tn = (tid & 15) << 3;

  float acc[8][8];
#pragma unroll
  for (int r = 0; r < 8; ++r)
#pragma unroll
    for (int c = 0; c < 8; ++c) acc[r][c] = 0.f;

  const int lr = tid >> 1;
  const int lk = (tid & 1) * 8;
  const int bkr = tid >> 4;
  const int bnc = (tid & 15) * 8;

  for (int k0 = 0; k0 < K; k0 += BKg) {
    {
      const float* ap = A + (long)(bm + lr) * K + k0 + lk;
      float4 a0 = *(const float4*)ap;
      float4 a1 = *(const float4*)(ap + 4);
      As[lk + 0][lr] = a0.x; As[lk + 1][lr] = a0.y; As[lk + 2][lr] = a0.z; As[lk + 3][lr] = a0.w;
      As[lk + 4][lr] = a1.x; As[lk + 5][lr] = a1.y; As[lk + 6][lr] = a1.z; As[lk + 7][lr] = a1.w;
    }
    if (TRANSB) {
      const float* bp = Bm + (long)(bn + lr) * K + k0 + lk;
      float4 b0 = *(const float4*)bp;
      float4 b1 = *(const float4*)(bp + 4);
      Bs[lk + 0][lr] = b0.x; Bs[lk + 1][lr] = b0.y; Bs[lk + 2][lr] = b0.z; Bs[lk + 3][lr] = b0.w;
      Bs[lk + 4][lr] = b1.x; Bs[lk + 5][lr] = b1.y; Bs[lk + 6][lr] = b1.z; Bs[lk + 7][lr] = b1.w;
    } else {
      const float* bp = Bm + (long)(k0 + bkr) * Nd + bn + bnc;
      float4 b0 = *(const float4*)bp;
      float4 b1 = *(const float4*)(bp + 4);
      *(float4*)&Bs[bkr][bnc] = b0;
      *(float4*)&Bs[bkr][bnc + 4] = b1;
    }
    __syncthreads();
#pragma unroll
    for (int kk = 0; kk < BKg; ++kk) {
      float4 a0 = *(const float4*)&As[kk][tm];
      float4 a1 = *(const float4*)&As[kk][tm + 4];
      float4 b0 = *(const float4*)&Bs[kk][tn];
      float4 b1 = *(const float4*)&Bs[kk][tn + 4];
      float av[8] = {a0.x, a0.y, a0.z, a0.w, a1.x, a1.y, a1.z, a1.w};
      float bv[8] = {b0.x, b0.y, b0.z, b0.w, b1.x, b1.y, b1.z, b1.w};
#pragma unroll
      for (int r = 0; r < 8; ++r)
#pragma unroll
        for (int c = 0; c < 8; ++c)
          acc[r][c] = fmaf(av[r], bv[c], acc[r][c]);
    }
    __syncthreads();
  }

#pragma unroll
  for (int r = 0; r < 8; ++r) {
    float* cp = C + (long)(bm + tm + r) * Nd + bn + tn;
#pragma unroll
    for (int c = 0; c < 8; ++c) {
      float v = acc[r][c];
      if (HASBIAS) v += bias[bn + tn + c];
      if (ACCUM) v += cp[c];
      if (RELU) v = fmaxf(v, 0.f);
      cp[c] = v;
    }
  }
}

// ---------------------------------------------------------------------------
// bf16 NT MFMA GEMM: C(MxN) f32 = A(MxK)bf16 @ Bt(NxK)bf16^T (+bias)(+accum)
// 128x128x32 tile, 4 waves (2x2), 16x16x32 MFMA, 4x4 frags/wave.
// ---------------------------------------------------------------------------
template<bool HASBIAS, bool ACCUM, bool RELU>
__global__ __launch_bounds__(256) void gemm_bf16_nt(
    const ushort* __restrict__ A, const ushort* __restrict__ Bt,
    const float* __restrict__ bias, float* __restrict__ C,
    int M, int N, int K, long sB, long sC, long sBias)
{
  const int bz = blockIdx.z;
  Bt += (long)bz * sB; C += (long)bz * sC;
  if (HASBIAS) bias += (long)bz * sBias;
  const int bn = blockIdx.x * 128, bm = blockIdx.y * 128;

  __shared__ ushort As[128][40];
  __shared__ ushort Bs[128][40];

  const int tid = threadIdx.x;
  const int wave = tid >> 6, lane = tid & 63;
  const int wm = (wave >> 1) * 64, wn = (wave & 1) * 64;
  const int fr = lane & 15;
  const int fk = (lane >> 4) * 8;

  f32x4 acc[4][4];
#pragma unroll
  for (int i = 0; i < 4; ++i)
#pragma unroll
    for (int j = 0; j < 4; ++j) acc[i][j] = (f32x4){0.f, 0.f, 0.f, 0.f};

  const int sr = tid >> 1;
  const int sq = (tid & 1) * 16;

  for (int k0 = 0; k0 < K; k0 += 32) {
    const uint4* ga = (const uint4*)(A + (long)(bm + sr) * K + k0 + sq);
    uint4 av0 = ga[0], av1 = ga[1];
    const uint4* gb = (const uint4*)(Bt + (long)(bn + sr) * K + k0 + sq);
    uint4 bv0 = gb[0], bv1 = gb[1];
    *(uint4*)&As[sr][sq] = av0;
    *(uint4*)&As[sr][sq + 8] = av1;
    *(uint4*)&Bs[sr][sq] = bv0;
    *(uint4*)&Bs[sr][sq + 8] = bv1;
    __syncthreads();

    bf16x8 af[4], bfr[4];
#pragma unroll
    for (int f = 0; f < 4; ++f) {
      af[f]  = *(const bf16x8*)&As[wm + f * 16 + fr][fk];
      bfr[f] = *(const bf16x8*)&Bs[wn + f * 16 + fr][fk];
    }
#pragma unroll
    for (int mf = 0; mf < 4; ++mf)
#pragma unroll
      for (int nf = 0; nf < 4; ++nf)
        acc[mf][nf] = __builtin_amdgcn_mfma_f32_16x16x32_bf16(
            af[mf], bfr[nf], acc[mf][nf], 0, 0, 0);
    __syncthreads();
  }

  float bv[4];
#pragma unroll
  for (int nf = 0; nf < 4; ++nf)
    bv[nf] = HASBIAS ? bias[bn + wn + nf * 16 + fr] : 0.f;

  const int crow0 = (lane >> 4) * 4;
#pragma unroll
  for (int mf = 0; mf < 4; ++mf)
#pragma unroll
    for (int r = 0; r < 4; ++r) {
      float* cp = C + (long)(bm + wm + mf * 16 + crow0 + r) * N + bn + wn;
#pragma unroll
      for (int nf = 0; nf < 4; ++nf) {
        float v = acc[mf][nf][r] + bv[nf];
        if (ACCUM) v += cp[nf * 16 + fr];
        if (RELU) v = fmaxf(v, 0.f);
        cp[nf * 16 + fr] = v;
      }
    }
}

// ---------------------------------------------------------------------------
// helpers
// ---------------------------------------------------------------------------
__device__ __forceinline__ unsigned short f2bf(float f) {
  unsigned u = __float_as_uint(f);
  u += 0x7fffu + ((u >> 16) & 1u);
  return (unsigned short)(u >> 16);
}
__device__ __forceinline__ float sigf(float x) { return 1.f / (1.f + expf(-x)); }

__device__ __forceinline__ int sdot4_(uint a, uint b, int c) {
#if __has_builtin(__builtin_amdgcn_sdot4)
  return __builtin_amdgcn_sdot4((int)a, (int)b, c, false);
#else
  int r = c;
  r += ((int)(a << 24) >> 24) * ((int)(b << 24) >> 24);
  r += ((int)(a << 16) >> 24) * ((int)(b << 16) >> 24);
  r += ((int)(a << 8)  >> 24) * ((int)(b << 8)  >> 24);
  r += ((int)a >> 24)         * ((int)b >> 24);
  return r;
#endif
}

// f32 -> bf16 convert (n multiple of 1024)
__global__ __launch_bounds__(256) void cvt_bf16_k(const float* __restrict__ src,
                                                  ushort* __restrict__ dst) {
  const long i = ((long)blockIdx.x * 256 + threadIdx.x) * 4;
  float4 v = *(const float4*)(src + i);
  ushort4 o;
  o.x = f2bf(v.x); o.y = f2bf(v.y); o.z = f2bf(v.z); o.w = f2bf(v.w);
  *(ushort4*)(dst + i) = o;
}

// Transpose + bf16: dst(C x R) = src(R x C)^T. R,C multiples of 32.
__global__ __launch_bounds__(256) void tp_bf16_k(const float* __restrict__ src,
                                                 ushort* __restrict__ dst,
                                                 int R, int C) {
  __shared__ float tile[32][33];
  const int c0 = blockIdx.x * 32, r0 = blockIdx.y * 32;
  const int tx = threadIdx.x & 31, ty = threadIdx.x >> 5;  // ty 0..7
#pragma unroll
  for (int j = 0; j < 4; ++j)
    tile[ty + j * 8][tx] = src[(long)(r0 + ty + j * 8) * C + c0 + tx];
  __syncthreads();
#pragma unroll
  for (int j = 0; j < 4; ++j)
    dst[(long)(c0 + ty + j * 8) * R + r0 + tx] = f2bf(tile[tx][ty + j * 8]);
}

// Whh (2,1024,256) f32 -> int8 [d][k4][gi] dwords + per-row scale [d][gi]
__global__ __launch_bounds__(256) void pack_whh_i8_k(const float* __restrict__ Whh,
                                                     uint* __restrict__ Wq,
                                                     float* __restrict__ fscale) {
  const int wid = (blockIdx.x * 256 + threadIdx.x) >> 6;  // 0..2047
  const int lane = threadIdx.x & 63;
  const int d = wid >> 10, gi = wid & 1023;
  const float* row = Whh + ((long)d * 1024 + gi) * 256 + lane * 4;
  float v0 = row[0], v1 = row[1], v2 = row[2], v3 = row[3];
  float am = fmaxf(fmaxf(fabsf(v0), fabsf(v1)), fmaxf(fabsf(v2), fabsf(v3)));
#pragma unroll
  for (int off = 32; off > 0; off >>= 1) am = fmaxf(am, __shfl_xor(am, off, 64));
  am = fmaxf(am, 1e-12f);
  const float inv = 127.f / am;
  int q0 = __float2int_rn(v0 * inv), q1 = __float2int_rn(v1 * inv);
  int q2 = __float2int_rn(v2 * inv), q3 = __float2int_rn(v3 * inv);
  uint w = (uint)(q0 & 255) | ((uint)(q1 & 255) << 8) |
           ((uint)(q2 & 255) << 16) | ((uint)(q3 & 255) << 24);
  Wq[((long)d * 64 + lane) * 1024 + gi] = w;
  if (lane == 0) fscale[d * 1024 + gi] = am / 127.f;
}

// ---------------------------------------------------------------------------
// LSTM v4: FULL Whh register-resident (64 int8-dwords/thread), int8 h via
// LDS broadcast, sdot4. 128 WGs = (dir, batch-row); 1024 thr = (gate, out-i).
// ---------------------------------------------------------------------------
__global__ __launch_bounds__(1024) void lstm4_k(
    const float* __restrict__ Xg,    // (2, 8192, 1024) x-part gate preacts
    const uint* __restrict__ Wq,     // (2, 64, 1024) int8-packed dwords
    const float* __restrict__ fscale,// (2, 1024)
    float* __restrict__ out)         // (128, 64, 512)
{
  const int bx = blockIdx.x;         // d*64 + b
  const int d = bx >> 6, b = bx & 63;
  const int tid = threadIdx.x;       // gi = g*256+i

  __shared__ uint hq[2][64];         // int8 h, double-buffered
  __shared__ float preactF[1024];

  // whole recurrent weight row in registers (64 VGPRs)
  uint w[64];
  const uint* wrow = Wq + (long)d * 65536 + tid;
#pragma unroll
  for (int k4 = 0; k4 < 64; ++k4) w[k4] = wrow[k4 * 1024];

  if (tid < 128) ((uint*)hq)[tid] = 0u;

  const float fsc = fscale[d * 1024 + tid] * (1.0f / 127.0f);
  const float* Xd = Xg + (long)d * 8192 * 1024;

  float c = 0.f;
  float x0 = 0.f, x1 = 0.f, x2 = 0.f, x3 = 0.f;
  if (tid < 256) {
    const float* xr = Xd + ((long)((d ? 127 : 0) * 64 + b)) * 1024;
    x0 = xr[tid]; x1 = xr[tid + 256]; x2 = xr[tid + 512]; x3 = xr[tid + 768];
  }
  __syncthreads();

  int cur = 0;
  for (int step = 0; step < 128; ++step) {
    const int t = d ? 127 - step : step;

    // prefetch next-step x gates (overlaps dot phase)
    float n0 = 0.f, n1 = 0.f, n2 = 0.f, n3 = 0.f;
    if (tid < 256 && step + 1 < 128) {
      const float* xr = Xd + ((long)((d ? 126 - step : step + 1) * 64 + b)) * 1024;
      n0 = xr[tid]; n1 = xr[tid + 256]; n2 = xr[tid + 512]; n3 = xr[tid + 768];
    }

    int acc = 0;
    const uint4* hrow = (const uint4*)hq[cur];
#pragma unroll
    for (int k16 = 0; k16 < 16; ++k16) {
      uint4 h4 = hrow[k16];
      acc = sdot4_(w[k16 * 4 + 0], h4.x, acc);
      acc = sdot4_(w[k16 * 4 + 1], h4.y, acc);
      acc = sdot4_(w[k16 * 4 + 2], h4.z, acc);
      acc = sdot4_(w[k16 * 4 + 3], h4.w, acc);
    }
    preactF[tid] = (float)acc * fsc;
    __syncthreads();

    if (tid < 256) {
      float p0 = x0 + preactF[tid];
      float p1 = x1 + preactF[tid + 256];
      float p2 = x2 + preactF[tid + 512];
      float p3 = x3 + preactF[tid + 768];
      const float ig = sigf(p0), fg = sigf(p1);
      const float gg = tanhf(p2), og = sigf(p3);
      c = fg * c + ig * gg;
      const float h = og * tanhf(c);
      out[((long)(t * 64 + b)) * 512 + (d << 8) + tid] = h;
      ((char*)hq[cur ^ 1])[tid] = (char)__float2int_rn(h * 127.f);
      x0 = n0; x1 = n1; x2 = n2; x3 = n3;
    }
    __syncthreads();
    cur ^= 1;
  }
}

// ---------------------------------------------------------------------------
// Edge attention softmax + window renorm. scores: (B, t, s)
// ---------------------------------------------------------------------------
__global__ __launch_bounds__(128) void edge_softmax_k(const float* __restrict__ scale,
                                                      float* __restrict__ scores) {
  const int bx = blockIdx.x;            // b*128 + t
  const int b = bx >> 7, t = bx & 127;
  const int s = threadIdx.x;
  __shared__ float red[128];
  const float v = scale[((long)(s * 64 + b)) * 128 + t];
  red[s] = v; __syncthreads();
  for (int off = 64; off > 0; off >>= 1) { if (s < off) red[s] = fmaxf(red[s], red[s + off]); __syncthreads(); }
  const float m = red[0]; __syncthreads();
  const float e = expf(v - m);
  red[s] = e; __syncthreads();
  for (int off = 64; off > 0; off >>= 1) { if (s < off) red[s] += red[s + off]; __syncthreads(); }
  const float esum = red[0]; __syncthreads();
  const float alpha = e / esum;
  const int dd = s - t;
  const bool inwin = (dd <= 10) && (dd >= -10);
  const float masked = alpha * (inwin ? 1.0f : 1e-10f);
  red[s] = masked; __syncthreads();
  for (int off = 64; off > 0; off >>= 1) { if (s < off) red[s] += red[s + off]; __syncthreads(); }
  const float msum = red[0];
  scores[(long)bx * 128 + s] = inwin ? (masked / msum) : 0.f;
}

// x b-major: f32 + bf16
__global__ __launch_bounds__(256) void xbuf_k(const float* __restrict__ feats,
                                              float* __restrict__ xb,
                                              ushort* __restrict__ xbf) {
  const int n = blockIdx.x;
  const int b = n >> 7, t = n & 127;
  const int tid = threadIdx.x;
  const float* src = feats + (long)(t * 64 + b) * 512;
  float v0 = src[tid], v1 = src[tid + 256];
  float* dst = xb + (long)n * 512;
  dst[tid] = v0; dst[tid + 256] = v1;
  ushort* dbf = xbf + (long)n * 512;
  dbf[tid] = f2bf(v0); dbf[tid + 256] = f2bf(v1);
}

// W_rel basis combination -> bf16 transposed (N=r*256+o rows, K=f cols)
__global__ __launch_bounds__(256) void wrel_k(const float* __restrict__ basis,
                                              const float* __restrict__ comp,
                                              ushort* __restrict__ wrel2t) {
  const int f = blockIdx.x;     // 0..511
  const int o = threadIdx.x;    // 0..255
  __shared__ float cs[240];
  if (o < 240) cs[o] = comp[o];
  __syncthreads();
  float acc[8];
#pragma unroll
  for (int r = 0; r < 8; ++r) acc[r] = 0.f;
  for (int bb = 0; bb < 30; ++bb) {
    const float v = basis[((long)bb * 512 + f) * 256 + o];
#pragma unroll
    for (int r = 0; r < 8; ++r) acc[r] = fmaf(cs[r * 30 + bb], v, acc[r]);
  }
#pragma unroll
  for (int r = 0; r < 8; ++r)
    wrel2t[((long)(r * 256 + o)) * 512 + f] = f2bf(acc[r]);
}

// RGCN message gather: h (f32) + hbf (bf16)
__global__ __launch_bounds__(256) void rgcn_gather_k(
    const float* __restrict__ xrel, const float* __restrict__ scores,
    const float* __restrict__ hroot, const int* __restrict__ spk,
    float* __restrict__ h, ushort* __restrict__ hbf)
{
  const int n = blockIdx.x;
  const int b = n >> 7, t = n & 127;
  const int o = threadIdx.x;
  const int lo = max(t - 10, 0), hi = min(t + 10, 127);
  const int cnt = hi - lo + 1;
  __shared__ int spks[21];
  __shared__ float wv[21];
  __shared__ int spkt_s;
  if (o < cnt) {
    spks[o] = spk[(lo + o) * 64 + b];
    wv[o] = scores[((long)(b * 128 + t)) * 128 + lo + o];
  }
  if (o == 0) spkt_s = spk[t * 64 + b];
  __syncthreads();
  const int spkt = spkt_s;
  float acc = hroot[(long)n * 256 + o];
  for (int q = 0; q < cnt; ++q) {
    const int s = lo + q;
    const int et = spkt * 4 + spks[q] * 2 + ((t < s) ? 0 : 1);
    acc = fmaf(xrel[(((long)(b * 128 + s)) * 8 + et) * 256 + o], wv[q], acc);
  }
  h[(long)n * 256 + o] = acc;
  hbf[(long)n * 256 + o] = f2bf(acc);
}

// GraphConv neighbor aggregation -> bf16
__global__ __launch_bounds__(256) void agg_k(const float* __restrict__ h,
                                             ushort* __restrict__ aggbf) {
  const int n = blockIdx.x;
  const int b = n >> 7, t = n & 127;
  const int o = threadIdx.x;
  const int lo = max(t - 10, 0), hi = min(t + 10, 127);
  float acc = 0.f;
  for (int s = lo; s <= hi; ++s) acc += h[((long)(b * 128 + s)) * 256 + o];
  aggbf[(long)n * 256 + o] = f2bf(acc);
}

// em = concat(x, h2): f32 + bf16
__global__ __launch_bounds__(256) void em_k(const float* __restrict__ xb,
                                            const float* __restrict__ h2,
                                            float* __restrict__ em,
                                            ushort* __restrict__ embf) {
  const int n = blockIdx.x;
  const int tid = threadIdx.x;
  const float v0 = xb[(long)n * 512 + tid];
  const float v1 = xb[(long)n * 512 + 256 + tid];
  const float v2 = h2[(long)n * 256 + tid];
  em[(long)n * 768 + tid] = v0;
  em[(long)n * 768 + 256 + tid] = v1;
  em[(long)n * 768 + 512 + tid] = v2;
  embf[(long)n * 768 + tid] = f2bf(v0);
  embf[(long)n * 768 + 256 + tid] = f2bf(v1);
  embf[(long)n * 768 + 512 + tid] = f2bf(v2);
}

__global__ __launch_bounds__(128) void match_softmax_k(float* __restrict__ logits,
                                                       const float* __restrict__ umask) {
  const int bx = blockIdx.x;           // b*128 + t
  const int b = bx >> 7;
  const int s = threadIdx.x;
  __shared__ float red[128];
  float* row = logits + (long)bx * 128;
  const float um = umask[b * 128 + s];
  const float v = tanhf(row[s] * um * um);
  red[s] = v; __syncthreads();
  for (int off = 64; off > 0; off >>= 1) { if (s < off) red[s] = fmaxf(red[s], red[s + off]); __syncthreads(); }
  const float m = red[0]; __syncthreads();
  const float e = expf(v - m);
  red[s] = e; __syncthreads();
  for (int off = 64; off > 0; off >>= 1) { if (s < off) red[s] += red[s + off]; __syncthreads(); }
  const float es = red[0]; __syncthreads();
  const float p = (e / es) * um;
  red[s] = p; __syncthreads();
  for (int off = 64; off > 0; off >>= 1) { if (s < off) red[s] += red[s + off]; __syncthreads(); }
  const float ps = red[0];
  row[s] = p / ps;
}

__global__ __launch_bounds__(256) void final_k(const float* __restrict__ hidden,
                                               const float* __restrict__ Ws,
                                               const float* __restrict__ bs,
                                               float* __restrict__ out) {
  __shared__ float wsl[256 * 6];
  const int tid = threadIdx.x;
#pragma unroll
  for (int j = 0; j < 6; ++j) wsl[tid * 6 + j] = Ws[tid * 6 + j];
  __syncthreads();
  const int wave = tid >> 6, lane = tid & 63;
  const int n = blockIdx.x * 4 + wave;
  const float4 hv = *(const float4*)&hidden[(long)n * 256 + lane * 4];
  const float hvv[4] = {hv.x, hv.y, hv.z, hv.w};
  float a[6];
#pragma unroll
  for (int c = 0; c < 6; ++c) a[c] = 0.f;
#pragma unroll
  for (int j = 0; j < 4; ++j)
#pragma unroll
    for (int c = 0; c < 6; ++c)
      a[c] = fmaf(hvv[j], wsl[(lane * 4 + j) * 6 + c], a[c]);
#pragma unroll
  for (int off = 32; off > 0; off >>= 1)
#pragma unroll
    for (int c = 0; c < 6; ++c)
      a[c] += __shfl_xor(a[c], off, 64);
  if (lane == 0) {
    float v[6], m = -1e30f;
#pragma unroll
    for (int c = 0; c < 6; ++c) { v[c] = a[c] + bs[c]; m = fmaxf(m, v[c]); }
    float sum = 0.f;
#pragma unroll
    for (int c = 0; c < 6; ++c) sum += expf(v[c] - m);
    const float lse = m + logf(sum);
#pragma unroll
    for (int c = 0; c < 6; ++c) out[(long)n * 6 + c] = v[c] - lse;
  }
}

// ---------------------------------------------------------------------------
// Orchestration
// ---------------------------------------------------------------------------
extern "C" void kernel_launch(void* const* d_in, const int* in_sizes, int n_in,
                              void* d_out, int out_size, void* d_ws, size_t ws_size,
                              hipStream_t stream) {
  const float* U        = (const float*)d_in[0];
  const float* umask    = (const float*)d_in[1];
  const float* Wih0     = (const float*)d_in[2];
  const float* Whh0     = (const float*)d_in[3];
  const float* b0       = (const float*)d_in[4];
  const float* Wih1     = (const float*)d_in[5];
  const float* Whh1     = (const float*)d_in[6];
  const float* b1       = (const float*)d_in[7];
  const float* W_scalar = (const float*)d_in[8];
  const float* basis    = (const float*)d_in[9];
  const float* comp     = (const float*)d_in[10];
  const float* W_root   = (const float*)d_in[11];
  const float* b_rgcn   = (const float*)d_in[12];
  const float* gc_W1    = (const float*)d_in[13];
  const float* gc_W2    = (const float*)d_in[14];
  const float* gc_b     = (const float*)d_in[15];
  const float* Wm       = (const float*)d_in[16];
  const float* bm       = (const float*)d_in[17];
  const float* Wl       = (const float*)d_in[18];
  const float* bl       = (const float*)d_in[19];
  const float* Wsw      = (const float*)d_in[20];
  const float* bsw      = (const float*)d_in[21];
  const int*   speakers = (const int*)d_in[22];

  float* ws = (float*)d_ws;
  // Regions (float offsets), reused across phases:
  float* gates   = ws + 0L;          // 16,777,216: X gates -> xrel -> em(0..6.29M)+xtr(6.29..12.58M)
  float* feats   = ws + 16777216L;   //  4,194,304: wih bf16 early -> L1 out -> att f32 (spans into xbuf)
  float* xbuf    = ws + 20971520L;   //  4,194,304: U bf16 early -> x f32 (dead after em_k)
  float* feats0  = ws + 25165824L;   //  4,194,304: L0 out -> xbf -> h/hbf/aggbf -> embf -> attbf
  float* scaleb  = ws + 29360128L;   //  1,048,576: scale -> logits -> hidden (spans scoresb)
  float* scoresb = ws + 30408704L;   //  1,048,576
  float* wrelr   = ws + 31457280L;   //  1,048,576: wrel2t bf16 (2048x512 us)
  float* hroot   = ws + 32505856L;   //  2,097,152: f0bf early -> hroot -> h2
  uint*  wq      = (uint*)(ws + 34603008L);   // 262,144 dwords
  float* fsc     = ws + 34865152L;            // 4,096
  float* wTr     = ws + 34869248L;            // 524,288 (transposed bf16 weights)

  ushort* ubf    = (ushort*)xbuf;
  ushort* wih0bf = (ushort*)feats;
  ushort* wih1bf = (ushort*)(feats + 1048576L);
  ushort* f0bf   = (ushort*)hroot;
  ushort* wrel2t = (ushort*)wrelr;
  ushort* wroott = (ushort*)wTr;                 // 131,072 us
  ushort* gcW1t  = wroott + 131072L;             //  65,536 us
  ushort* gcW2t  = gcW1t + 65536L;               //  65,536 us
  ushort* Wmt    = gcW2t + 65536L;               // 589,824 us
  ushort* Wlt    = Wmt + 589824L;                // 196,608 us

  // feats0 sub-lives (all disjoint in time):
  ushort* xbf     = (ushort*)feats0;             // xbuf_k -> xrel gemm
  float*  hb      = feats0;                      // rgcn -> agg/gc
  ushort* hbf     = (ushort*)(feats0 + 2097152L);
  ushort* aggbf   = (ushort*)(feats0 + 3145728L);
  ushort* embf    = (ushort*)feats0;             // em_k -> Wm gemm
  ushort* attbf   = (ushort*)feats0;             // att cvt -> classifier gemm

  float*  xrel    = gates;
  float*  h2b     = hroot;
  float*  emb     = gates;
  float*  xtrb    = gates + 6291456L;
  float*  logitsb = scaleb;
  float*  attb    = feats;                       // 6.29M f: spans feats + xbuf[0..2.1M) (both dead)
  float*  hiddenb = scaleb;

  // --- weight prep ---
  pack_whh_i8_k<<<512, 256, 0, stream>>>(Whh0, wq, fsc);
  pack_whh_i8_k<<<512, 256, 0, stream>>>(Whh1, wq + 131072, fsc + 2048);
  cvt_bf16_k<<<8192, 256, 0, stream>>>(U, ubf);
  cvt_bf16_k<<<2048, 256, 0, stream>>>(Wih0, wih0bf);
  cvt_bf16_k<<<1024, 256, 0, stream>>>(Wih1, wih1bf);
  tp_bf16_k<<<dim3(8, 16), 256, 0, stream>>>(W_root, wroott, 512, 256);
  tp_bf16_k<<<dim3(8, 8), 256, 0, stream>>>(gc_W1, gcW1t, 256, 256);
  tp_bf16_k<<<dim3(8, 8), 256, 0, stream>>>(gc_W2, gcW2t, 256, 256);
  tp_bf16_k<<<dim3(24, 24), 256, 0, stream>>>(Wm, Wmt, 768, 768);
  tp_bf16_k<<<dim3(8, 24), 256, 0, stream>>>(Wl, Wlt, 768, 256);
  wrel_k<<<512, 256, 0, stream>>>(basis, comp, wrel2t);

  // --- layer 0 ---
  gemm_bf16_nt<true, false, false><<<dim3(8, 64, 2), 256, 0, stream>>>(
      ubf, wih0bf, b0, gates, 8192, 1024, 1024, 1048576L, 8388608L, 1024L);
  lstm4_k<<<128, 1024, 0, stream>>>(gates, wq, fsc, feats0);

  // --- layer 1 ---
  cvt_bf16_k<<<4096, 256, 0, stream>>>(feats0, f0bf);
  gemm_bf16_nt<true, false, false><<<dim3(8, 64, 2), 256, 0, stream>>>(
      f0bf, wih1bf, b1, gates, 8192, 1024, 512, 524288L, 8388608L, 1024L);
  lstm4_k<<<128, 1024, 0, stream>>>(gates, wq + 131072, fsc + 2048, feats);

  // --- edge attention scores ---
  gemm_k<false, false, false, false><<<dim3(1, 64, 1), 256, 0, stream>>>(
      feats, W_scalar, nullptr, scaleb, 8192, 128, 512, 0L, 0L, 0L, 0L);
  edge_softmax_k<<<8192, 128, 0, stream>>>(scaleb, scoresb);

  // --- node features (b-major) + RGCN ---
  xbuf_k<<<8192, 256, 0, stream>>>(feats, xbuf, xbf);
  gemm_bf16_nt<true, false, false><<<dim3(2, 64, 1), 256, 0, stream>>>(
      xbf, wroott, b_rgcn, hroot, 8192, 256, 512, 0L, 0L, 0L);
  gemm_bf16_nt<false, false, false><<<dim3(16, 64, 1), 256, 0, stream>>>(
      xbf, wrel2t, nullptr, xrel, 8192, 2048, 512, 0L, 0L, 0L);
  rgcn_gather_k<<<8192, 256, 0, stream>>>(xrel, scoresb, hroot, speakers, hb, hbf);

  // --- GraphConv ---
  agg_k<<<8192, 256, 0, stream>>>(hb, aggbf);
  gemm_bf16_nt<true, false, false><<<dim3(2, 64, 1), 256, 0, stream>>>(
      hbf, gcW1t, gc_b, h2b, 8192, 256, 256, 0L, 0L, 0L);
  gemm_bf16_nt<false, true, false><<<dim3(2, 64, 1), 256, 0, stream>>>(
      aggbf, gcW2t, nullptr, h2b, 8192, 256, 256, 0L, 0L, 0L);

  // --- matching attention ---
  em_k<<<8192, 256, 0, stream>>>(xbuf, h2b, emb, embf);
  gemm_bf16_nt<true, false, false><<<dim3(6, 64, 1), 256, 0, stream>>>(
      embf, Wmt, bm, xtrb, 8192, 768, 768, 0L, 0L, 0L);
  gemm_k<true, false, false, false><<<dim3(1, 1, 64), 256, 0, stream>>>(
      xtrb, emb, nullptr, logitsb, 128, 128, 768, 98304L, 98304L, 16384L, 0L);
  match_softmax_k<<<8192, 128, 0, stream>>>(logitsb, umask);
  gemm_k<false, false, false, false><<<dim3(6, 1, 64), 256, 0, stream>>>(
      logitsb, emb, nullptr, attb, 128, 768, 128, 16384L, 98304L, 98304L, 0L);

  // --- classifier ---
  cvt_bf16_k<<<6144, 256, 0, stream>>>(attb, attbf);
  gemm_bf16_nt<true, false, true><<<dim3(2, 64, 1), 256, 0, stream>>>(
      attbf, Wlt, bl, hiddenb, 8192, 256, 768, 0L, 0L, 0L);
  final_k<<<2048, 256, 0, stream>>>(hiddenb, Wsw, bsw, (float*)d_out);
}

// Round 6
// 676.039 us; speedup vs baseline: 5.2259x; 1.3258x over previous
//
#include <hip/hip_runtime.h>
#include <cstdint>

// Model dims (fixed): L=128, B=64, DM=1024, H=256, F=512, HID=256, MEM=768,
// N=B*L=8192, NC=6, R=8, NB=30, WIN=10

typedef __attribute__((ext_vector_type(8))) short bf16x8;
typedef __attribute__((ext_vector_type(4))) float f32x4;

// ---------------------------------------------------------------------------
// bf16 NT MFMA GEMM: C(MxN) = A(MxK)bf16 @ Bt(NxK)bf16^T (+bias)(+accum)
// C is f32, or bf16 when OUTBF. Batched via blockIdx.z (sA/sB/sC/sBias elem
// strides). 128x128x32 tile, 4 waves (2x2), 16x16x32 MFMA, 4x4 frags/wave.
// ---------------------------------------------------------------------------
template<bool HASBIAS, bool ACCUM, bool RELU, bool OUTBF>
__global__ __launch_bounds__(256) void gemm_bf16_nt(
    const ushort* __restrict__ A, const ushort* __restrict__ Bt,
    const float* __restrict__ bias, void* __restrict__ Cv,
    int M, int N, int K, long sA, long sB, long sC, long sBias)
{
  const int bz = blockIdx.z;
  A += (long)bz * sA;
  Bt += (long)bz * sB;
  if (HASBIAS) bias += (long)bz * sBias;
  float*  Cf = OUTBF ? nullptr : ((float*)Cv + (long)bz * sC);
  ushort* Cb = OUTBF ? ((ushort*)Cv + (long)bz * sC) : nullptr;

  const int bn = blockIdx.x * 128, bm = blockIdx.y * 128;

  __shared__ ushort As[128][40];   // +8 pad: benign 2-way bank aliasing
  __shared__ ushort Bs[128][40];

  const int tid = threadIdx.x;
  const int wave = tid >> 6, lane = tid & 63;
  const int wm = (wave >> 1) * 64, wn = (wave & 1) * 64;
  const int fr = lane & 15;
  const int fk = (lane >> 4) * 8;

  f32x4 acc[4][4];
#pragma unroll
  for (int i = 0; i < 4; ++i)
#pragma unroll
    for (int j = 0; j < 4; ++j) acc[i][j] = (f32x4){0.f, 0.f, 0.f, 0.f};

  const int sr = tid >> 1;
  const int sq = (tid & 1) * 16;

  for (int k0 = 0; k0 < K; k0 += 32) {
    const uint4* ga = (const uint4*)(A + (long)(bm + sr) * K + k0 + sq);
    uint4 av0 = ga[0], av1 = ga[1];
    const uint4* gb = (const uint4*)(Bt + (long)(bn + sr) * K + k0 + sq);
    uint4 bv0 = gb[0], bv1 = gb[1];
    *(uint4*)&As[sr][sq] = av0;
    *(uint4*)&As[sr][sq + 8] = av1;
    *(uint4*)&Bs[sr][sq] = bv0;
    *(uint4*)&Bs[sr][sq + 8] = bv1;
    __syncthreads();

    bf16x8 af[4], bfr[4];
#pragma unroll
    for (int f = 0; f < 4; ++f) {
      af[f]  = *(const bf16x8*)&As[wm + f * 16 + fr][fk];
      bfr[f] = *(const bf16x8*)&Bs[wn + f * 16 + fr][fk];
    }
#pragma unroll
    for (int mf = 0; mf < 4; ++mf)
#pragma unroll
      for (int nf = 0; nf < 4; ++nf)
        acc[mf][nf] = __builtin_amdgcn_mfma_f32_16x16x32_bf16(
            af[mf], bfr[nf], acc[mf][nf], 0, 0, 0);
    __syncthreads();
  }

  float bv[4];
#pragma unroll
  for (int nf = 0; nf < 4; ++nf)
    bv[nf] = HASBIAS ? bias[bn + wn + nf * 16 + fr] : 0.f;

  const int crow0 = (lane >> 4) * 4;
#pragma unroll
  for (int mf = 0; mf < 4; ++mf)
#pragma unroll
    for (int r = 0; r < 4; ++r) {
      const long roff = (long)(bm + wm + mf * 16 + crow0 + r) * N + bn + wn;
#pragma unroll
      for (int nf = 0; nf < 4; ++nf) {
        float v = acc[mf][nf][r] + bv[nf];
        if (OUTBF) {
          unsigned u = __float_as_uint(v);
          u += 0x7fffu + ((u >> 16) & 1u);
          Cb[roff + nf * 16 + fr] = (ushort)(u >> 16);
        } else {
          if (ACCUM) v += Cf[roff + nf * 16 + fr];
          if (RELU) v = fmaxf(v, 0.f);
          Cf[roff + nf * 16 + fr] = v;
        }
      }
    }
}

// ---------------------------------------------------------------------------
// helpers
// ---------------------------------------------------------------------------
__device__ __forceinline__ unsigned short f2bf(float f) {
  unsigned u = __float_as_uint(f);
  u += 0x7fffu + ((u >> 16) & 1u);
  return (unsigned short)(u >> 16);
}
__device__ __forceinline__ float fast_sig(float x) {
  return __builtin_amdgcn_rcpf(1.f + __expf(-x));
}
__device__ __forceinline__ float fast_tanh(float x) {
  const float xc = fminf(fmaxf(x, -15.f), 15.f);
  const float t = __expf(2.f * xc);
  return (t - 1.f) * __builtin_amdgcn_rcpf(t + 1.f);
}

__device__ __forceinline__ int sdot4_(uint a, uint b, int c) {
#if __has_builtin(__builtin_amdgcn_sdot4)
  return __builtin_amdgcn_sdot4((int)a, (int)b, c, false);
#else
  int r = c;
  r += ((int)(a << 24) >> 24) * ((int)(b << 24) >> 24);
  r += ((int)(a << 16) >> 24) * ((int)(b << 16) >> 24);
  r += ((int)(a << 8)  >> 24) * ((int)(b << 8)  >> 24);
  r += ((int)a >> 24)         * ((int)b >> 24);
  return r;
#endif
}

// f32 -> bf16 convert (n multiple of 1024)
__global__ __launch_bounds__(256) void cvt_bf16_k(const float* __restrict__ src,
                                                  ushort* __restrict__ dst) {
  const long i = ((long)blockIdx.x * 256 + threadIdx.x) * 4;
  float4 v = *(const float4*)(src + i);
  ushort4 o;
  o.x = f2bf(v.x); o.y = f2bf(v.y); o.z = f2bf(v.z); o.w = f2bf(v.w);
  *(ushort4*)(dst + i) = o;
}

// Transpose + bf16: dst(C x R) = src(R x C)^T. R,C multiples of 32.
__global__ __launch_bounds__(256) void tp_bf16_k(const float* __restrict__ src,
                                                 ushort* __restrict__ dst,
                                                 int R, int C) {
  __shared__ float tile[32][33];
  const int c0 = blockIdx.x * 32, r0 = blockIdx.y * 32;
  const int tx = threadIdx.x & 31, ty = threadIdx.x >> 5;  // ty 0..7
#pragma unroll
  for (int j = 0; j < 4; ++j)
    tile[ty + j * 8][tx] = src[(long)(r0 + ty + j * 8) * C + c0 + tx];
  __syncthreads();
#pragma unroll
  for (int j = 0; j < 4; ++j)
    dst[(long)(c0 + ty + j * 8) * R + r0 + tx] = f2bf(tile[tx][ty + j * 8]);
}

// Batched ushort transpose: dst[b](C x R) = src[b](R x C)^T, R=128, C=768.
__global__ __launch_bounds__(256) void emt_k(const ushort* __restrict__ src,
                                             ushort* __restrict__ dst) {
  __shared__ ushort tile[32][33];
  const int c0 = blockIdx.x * 32;   // col in src (0..767)
  const int r0 = blockIdx.y * 32;   // row in src (0..127)
  const int b = blockIdx.z;
  const ushort* s = src + (long)b * 98304;
  ushort* d = dst + (long)b * 98304;
  const int tx = threadIdx.x & 31, ty = threadIdx.x >> 5;
#pragma unroll
  for (int j = 0; j < 4; ++j)
    tile[ty + j * 8][tx] = s[(long)(r0 + ty + j * 8) * 768 + c0 + tx];
  __syncthreads();
#pragma unroll
  for (int j = 0; j < 4; ++j)
    d[(long)(c0 + ty + j * 8) * 128 + r0 + tx] = tile[tx][ty + j * 8];
}

// Whh (2,1024,256) f32 -> int8 [d][k4][gi] dwords + per-row scale [d][gi]
__global__ __launch_bounds__(256) void pack_whh_i8_k(const float* __restrict__ Whh,
                                                     uint* __restrict__ Wq,
                                                     float* __restrict__ fscale) {
  const int wid = (blockIdx.x * 256 + threadIdx.x) >> 6;  // 0..2047
  const int lane = threadIdx.x & 63;
  const int d = wid >> 10, gi = wid & 1023;
  const float* row = Whh + ((long)d * 1024 + gi) * 256 + lane * 4;
  float v0 = row[0], v1 = row[1], v2 = row[2], v3 = row[3];
  float am = fmaxf(fmaxf(fabsf(v0), fabsf(v1)), fmaxf(fabsf(v2), fabsf(v3)));
#pragma unroll
  for (int off = 32; off > 0; off >>= 1) am = fmaxf(am, __shfl_xor(am, off, 64));
  am = fmaxf(am, 1e-12f);
  const float inv = 127.f / am;
  int q0 = __float2int_rn(v0 * inv), q1 = __float2int_rn(v1 * inv);
  int q2 = __float2int_rn(v2 * inv), q3 = __float2int_rn(v3 * inv);
  uint w = (uint)(q0 & 255) | ((uint)(q1 & 255) << 8) |
           ((uint)(q2 & 255) << 16) | ((uint)(q3 & 255) << 24);
  Wq[((long)d * 64 + lane) * 1024 + gi] = w;
  if (lane == 0) fscale[d * 1024 + gi] = am / 127.f;
}

// ---------------------------------------------------------------------------
// LSTM v4b: FULL Whh register-resident (64 int8 dwords/thread), int8 h via
// LDS broadcast, sdot4; bf16 output. 128 WGs = (dir, b); 1024 thr = (gate,i).
// ---------------------------------------------------------------------------
__global__ __launch_bounds__(1024) void lstm4_k(
    const float* __restrict__ Xg,    // (2, 8192, 1024) x-part gate preacts
    const uint* __restrict__ Wq,     // (2, 64, 1024) int8-packed dwords
    const float* __restrict__ fscale,// (2, 1024)
    ushort* __restrict__ out)        // (128, 64, 512) bf16
{
  const int bx = blockIdx.x;         // d*64 + b
  const int d = bx >> 6, b = bx & 63;
  const int tid = threadIdx.x;       // gi = g*256+i

  __shared__ uint hq[2][64];         // int8 h, double-buffered
  __shared__ float preactF[1024];

  uint w[64];
  const uint* wrow = Wq + (long)d * 65536 + tid;
#pragma unroll
  for (int k4 = 0; k4 < 64; ++k4) w[k4] = wrow[k4 * 1024];

  if (tid < 128) ((uint*)hq)[tid] = 0u;

  const float fsc = fscale[d * 1024 + tid] * (1.0f / 127.0f);
  const float* Xd = Xg + (long)d * 8192 * 1024;

  float c = 0.f;
  float x0 = 0.f, x1 = 0.f, x2 = 0.f, x3 = 0.f;
  if (tid < 256) {
    const float* xr = Xd + ((long)((d ? 127 : 0) * 64 + b)) * 1024;
    x0 = xr[tid]; x1 = xr[tid + 256]; x2 = xr[tid + 512]; x3 = xr[tid + 768];
  }
  __syncthreads();

  int cur = 0;
  for (int step = 0; step < 128; ++step) {
    const int t = d ? 127 - step : step;

    float n0 = 0.f, n1 = 0.f, n2 = 0.f, n3 = 0.f;
    if (tid < 256 && step + 1 < 128) {
      const float* xr = Xd + ((long)((d ? 126 - step : step + 1) * 64 + b)) * 1024;
      n0 = xr[tid]; n1 = xr[tid + 256]; n2 = xr[tid + 512]; n3 = xr[tid + 768];
    }

    int acc = 0;
    const uint4* hrow = (const uint4*)hq[cur];
#pragma unroll
    for (int k16 = 0; k16 < 16; ++k16) {
      uint4 h4 = hrow[k16];
      acc = sdot4_(w[k16 * 4 + 0], h4.x, acc);
      acc = sdot4_(w[k16 * 4 + 1], h4.y, acc);
      acc = sdot4_(w[k16 * 4 + 2], h4.z, acc);
      acc = sdot4_(w[k16 * 4 + 3], h4.w, acc);
    }
    preactF[tid] = (float)acc * fsc;
    __syncthreads();

    if (tid < 256) {
      float p0 = x0 + preactF[tid];
      float p1 = x1 + preactF[tid + 256];
      float p2 = x2 + preactF[tid + 512];
      float p3 = x3 + preactF[tid + 768];
      const float ig = fast_sig(p0), fg = fast_sig(p1);
      const float gg = fast_tanh(p2), og = fast_sig(p3);
      c = fg * c + ig * gg;
      const float h = og * fast_tanh(c);
      out[((long)(t * 64 + b)) * 512 + (d << 8) + tid] = f2bf(h);
      ((char*)hq[cur ^ 1])[tid] = (char)__float2int_rn(h * 127.f);
      x0 = n0; x1 = n1; x2 = n2; x3 = n3;
    }
    __syncthreads();
    cur ^= 1;
  }
}

// ---------------------------------------------------------------------------
// Edge attention softmax + window renorm. scores: (B, t, s)
// ---------------------------------------------------------------------------
__global__ __launch_bounds__(128) void edge_softmax_k(const float* __restrict__ scale,
                                                      float* __restrict__ scores) {
  const int bx = blockIdx.x;            // b*128 + t
  const int b = bx >> 7, t = bx & 127;
  const int s = threadIdx.x;
  __shared__ float red[128];
  const float v = scale[((long)(s * 64 + b)) * 128 + t];
  red[s] = v; __syncthreads();
  for (int off = 64; off > 0; off >>= 1) { if (s < off) red[s] = fmaxf(red[s], red[s + off]); __syncthreads(); }
  const float m = red[0]; __syncthreads();
  const float e = expf(v - m);
  red[s] = e; __syncthreads();
  for (int off = 64; off > 0; off >>= 1) { if (s < off) red[s] += red[s + off]; __syncthreads(); }
  const float esum = red[0]; __syncthreads();
  const float alpha = e / esum;
  const int dd = s - t;
  const bool inwin = (dd <= 10) && (dd >= -10);
  const float masked = alpha * (inwin ? 1.0f : 1e-10f);
  red[s] = masked; __syncthreads();
  for (int off = 64; off > 0; off >>= 1) { if (s < off) red[s] += red[s + off]; __syncthreads(); }
  const float msum = red[0];
  scores[(long)bx * 128 + s] = inwin ? (masked / msum) : 0.f;
}

// x b-major reorder (bf16 in, bf16 out)
__global__ __launch_bounds__(256) void xbuf_k(const ushort* __restrict__ featsbf,
                                              ushort* __restrict__ xbf) {
  const int n = blockIdx.x;
  const int b = n >> 7, t = n & 127;
  const int tid = threadIdx.x;
  const ushort* src = featsbf + (long)(t * 64 + b) * 512;
  ushort* dst = xbf + (long)n * 512;
  dst[tid] = src[tid];
  dst[tid + 256] = src[tid + 256];
}

// W_rel basis combination -> bf16 transposed (N=r*256+o rows, K=f cols)
__global__ __launch_bounds__(256) void wrel_k(const float* __restrict__ basis,
                                              const float* __restrict__ comp,
                                              ushort* __restrict__ wrel2t) {
  const int f = blockIdx.x;     // 0..511
  const int o = threadIdx.x;    // 0..255
  __shared__ float cs[240];
  if (o < 240) cs[o] = comp[o];
  __syncthreads();
  float acc[8];
#pragma unroll
  for (int r = 0; r < 8; ++r) acc[r] = 0.f;
  for (int bb = 0; bb < 30; ++bb) {
    const float v = basis[((long)bb * 512 + f) * 256 + o];
#pragma unroll
    for (int r = 0; r < 8; ++r) acc[r] = fmaf(cs[r * 30 + bb], v, acc[r]);
  }
#pragma unroll
  for (int r = 0; r < 8; ++r)
    wrel2t[((long)(r * 256 + o)) * 512 + f] = f2bf(acc[r]);
}

// RGCN message gather: h (f32) + hbf (bf16)
__global__ __launch_bounds__(256) void rgcn_gather_k(
    const float* __restrict__ xrel, const float* __restrict__ scores,
    const float* __restrict__ hroot, const int* __restrict__ spk,
    float* __restrict__ h, ushort* __restrict__ hbf)
{
  const int n = blockIdx.x;
  const int b = n >> 7, t = n & 127;
  const int o = threadIdx.x;
  const int lo = max(t - 10, 0), hi = min(t + 10, 127);
  const int cnt = hi - lo + 1;
  __shared__ int spks[21];
  __shared__ float wv[21];
  __shared__ int spkt_s;
  if (o < cnt) {
    spks[o] = spk[(lo + o) * 64 + b];
    wv[o] = scores[((long)(b * 128 + t)) * 128 + lo + o];
  }
  if (o == 0) spkt_s = spk[t * 64 + b];
  __syncthreads();
  const int spkt = spkt_s;
  float acc = hroot[(long)n * 256 + o];
  for (int q = 0; q < cnt; ++q) {
    const int s = lo + q;
    const int et = spkt * 4 + spks[q] * 2 + ((t < s) ? 0 : 1);
    acc = fmaf(xrel[(((long)(b * 128 + s)) * 8 + et) * 256 + o], wv[q], acc);
  }
  h[(long)n * 256 + o] = acc;
  hbf[(long)n * 256 + o] = f2bf(acc);
}

// GraphConv neighbor aggregation -> bf16
__global__ __launch_bounds__(256) void agg_k(const float* __restrict__ h,
                                             ushort* __restrict__ aggbf) {
  const int n = blockIdx.x;
  const int b = n >> 7, t = n & 127;
  const int o = threadIdx.x;
  const int lo = max(t - 10, 0), hi = min(t + 10, 127);
  float acc = 0.f;
  for (int s = lo; s <= hi; ++s) acc += h[((long)(b * 128 + s)) * 256 + o];
  aggbf[(long)n * 256 + o] = f2bf(acc);
}

// embf = concat(xbf, bf16(h2))
__global__ __launch_bounds__(256) void em_k(const ushort* __restrict__ xbf,
                                            const float* __restrict__ h2,
                                            ushort* __restrict__ embf) {
  const int n = blockIdx.x;
  const int tid = threadIdx.x;
  embf[(long)n * 768 + tid] = xbf[(long)n * 512 + tid];
  embf[(long)n * 768 + 256 + tid] = xbf[(long)n * 512 + 256 + tid];
  embf[(long)n * 768 + 512 + tid] = f2bf(h2[(long)n * 256 + tid]);
}

// Matching attention probs: logits f32 in, bf16 a out
__global__ __launch_bounds__(128) void match_softmax_k(const float* __restrict__ logits,
                                                       const float* __restrict__ umask,
                                                       ushort* __restrict__ abf) {
  const int bx = blockIdx.x;           // b*128 + t
  const int b = bx >> 7;
  const int s = threadIdx.x;
  __shared__ float red[128];
  const float* row = logits + (long)bx * 128;
  const float um = umask[b * 128 + s];
  const float v = tanhf(row[s] * um * um);
  red[s] = v; __syncthreads();
  for (int off = 64; off > 0; off >>= 1) { if (s < off) red[s] = fmaxf(red[s], red[s + off]); __syncthreads(); }
  const float m = red[0]; __syncthreads();
  const float e = expf(v - m);
  red[s] = e; __syncthreads();
  for (int off = 64; off > 0; off >>= 1) { if (s < off) red[s] += red[s + off]; __syncthreads(); }
  const float es = red[0]; __syncthreads();
  const float p = (e / es) * um;
  red[s] = p; __syncthreads();
  for (int off = 64; off > 0; off >>= 1) { if (s < off) red[s] += red[s + off]; __syncthreads(); }
  const float ps = red[0];
  abf[(long)bx * 128 + s] = f2bf(p / ps);
}

__global__ __launch_bounds__(256) void final_k(const float* __restrict__ hidden,
                                               const float* __restrict__ Ws,
                                               const float* __restrict__ bs,
                                               float* __restrict__ out) {
  __shared__ float wsl[256 * 6];
  const int tid = threadIdx.x;
#pragma unroll
  for (int j = 0; j < 6; ++j) wsl[tid * 6 + j] = Ws[tid * 6 + j];
  __syncthreads();
  const int wave = tid >> 6, lane = tid & 63;
  const int n = blockIdx.x * 4 + wave;
  const float4 hv = *(const float4*)&hidden[(long)n * 256 + lane * 4];
  const float hvv[4] = {hv.x, hv.y, hv.z, hv.w};
  float a[6];
#pragma unroll
  for (int c = 0; c < 6; ++c) a[c] = 0.f;
#pragma unroll
  for (int j = 0; j < 4; ++j)
#pragma unroll
    for (int c = 0; c < 6; ++c)
      a[c] = fmaf(hvv[j], wsl[(lane * 4 + j) * 6 + c], a[c]);
#pragma unroll
  for (int off = 32; off > 0; off >>= 1)
#pragma unroll
    for (int c = 0; c < 6; ++c)
      a[c] += __shfl_xor(a[c], off, 64);
  if (lane == 0) {
    float v[6], m = -1e30f;
#pragma unroll
    for (int c = 0; c < 6; ++c) { v[c] = a[c] + bs[c]; m = fmaxf(m, v[c]); }
    float sum = 0.f;
#pragma unroll
    for (int c = 0; c < 6; ++c) sum += expf(v[c] - m);
    const float lse = m + logf(sum);
#pragma unroll
    for (int c = 0; c < 6; ++c) out[(long)n * 6 + c] = v[c] - lse;
  }
}

// ---------------------------------------------------------------------------
// Orchestration
// ---------------------------------------------------------------------------
extern "C" void kernel_launch(void* const* d_in, const int* in_sizes, int n_in,
                              void* d_out, int out_size, void* d_ws, size_t ws_size,
                              hipStream_t stream) {
  const float* U        = (const float*)d_in[0];
  const float* umask    = (const float*)d_in[1];
  const float* Wih0     = (const float*)d_in[2];
  const float* Whh0     = (const float*)d_in[3];
  const float* b0       = (const float*)d_in[4];
  const float* Wih1     = (const float*)d_in[5];
  const float* Whh1     = (const float*)d_in[6];
  const float* b1       = (const float*)d_in[7];
  const float* W_scalar = (const float*)d_in[8];
  const float* basis    = (const float*)d_in[9];
  const float* comp     = (const float*)d_in[10];
  const float* W_root   = (const float*)d_in[11];
  const float* b_rgcn   = (const float*)d_in[12];
  const float* gc_W1    = (const float*)d_in[13];
  const float* gc_W2    = (const float*)d_in[14];
  const float* gc_b     = (const float*)d_in[15];
  const float* Wm       = (const float*)d_in[16];
  const float* bm       = (const float*)d_in[17];
  const float* Wl       = (const float*)d_in[18];
  const float* bl       = (const float*)d_in[19];
  const float* Wsw      = (const float*)d_in[20];
  const float* bsw      = (const float*)d_in[21];
  const int*   speakers = (const int*)d_in[22];

  float* ws = (float*)d_ws;
  // Regions (float offsets), reused across phases (lifetimes audited):
  float* gates   = ws + 0L;          // 16.78M f: gates0/1 -> xrel -> xtrbf
  float* feats   = ws + 16777216L;   //  4.19M f: wih0bf/wih1bf -> featsbf -> attbf
  float* xbuf    = ws + 20971520L;   //  4.19M f: ubf -> xbf -> emT
  float* feats0  = ws + 25165824L;   //  4.19M f: f0bf -> h/hbf/aggbf -> embf
  float* scaleb  = ws + 29360128L;   //  1.05M f: scale -> logits -> hidden(lo)
  float* scoresb = ws + 30408704L;   //  1.05M f: wscT -> edge scores -> abf -> hidden(hi)
  float* wrelr   = ws + 31457280L;   //  1.05M f: wrel2t bf16
  float* hroot   = ws + 32505856L;   //  2.10M f: hroot -> h2
  uint*  wq      = (uint*)(ws + 34603008L);   // 262,144 dwords
  float* fsc     = ws + 34865152L;            // 4,096
  float* wTr     = ws + 34869248L;            // 524,288 f (transposed bf16 weights)

  ushort* ubf    = (ushort*)xbuf;
  ushort* wih0bf = (ushort*)feats;               // [0..1.05M f)
  ushort* wih1bf = (ushort*)(feats + 1048576L);  // [1.05..1.57M f)
  ushort* featsbf= (ushort*)(feats + 2097152L);  // [2.1..4.19M f)
  ushort* f0bf   = (ushort*)feats0;              // [0..2.1M f)
  ushort* xbf    = (ushort*)xbuf;                // [0..2.1M f) (ubf dead)
  ushort* wrel2t = (ushort*)wrelr;
  ushort* wroott = (ushort*)wTr;                 // 131,072 us
  ushort* gcW1t  = wroott + 131072L;             //  65,536 us
  ushort* gcW2t  = gcW1t + 65536L;               //  65,536 us
  ushort* Wmt    = gcW2t + 65536L;               // 589,824 us
  ushort* Wlt    = Wmt + 589824L;                // 196,608 us
  ushort* wscT   = (ushort*)scoresb;             // 65,536 us (dead before edge_softmax)

  float*  hb      = feats0;                      // f32 [0..2.1M f)
  ushort* hbf     = (ushort*)(feats0 + 2097152L);
  ushort* aggbf   = (ushort*)(feats0 + 3145728L);
  ushort* embf    = (ushort*)feats0;             // 6.29M us [0..3.15M f)
  ushort* emT     = (ushort*)xbuf;               // 6.29M us [0..3.15M f) (xbf dead)
  ushort* xtrbf   = (ushort*)gates;              // 6.29M us (xrel dead)
  ushort* abf     = (ushort*)scoresb;            // 1.05M us (edge scores dead)
  ushort* attbf   = (ushort*)feats;              // 6.29M us [0..3.15M f) (featsbf dead)

  float*  xrel    = gates;
  float*  h2b     = hroot;
  float*  logitsb = scaleb;
  float*  hiddenb = scaleb;                      // 2.1M f spans scaleb+scoresb

  // --- weight prep ---
  pack_whh_i8_k<<<512, 256, 0, stream>>>(Whh0, wq, fsc);
  pack_whh_i8_k<<<512, 256, 0, stream>>>(Whh1, wq + 131072, fsc + 2048);
  cvt_bf16_k<<<8192, 256, 0, stream>>>(U, ubf);
  cvt_bf16_k<<<2048, 256, 0, stream>>>(Wih0, wih0bf);
  cvt_bf16_k<<<1024, 256, 0, stream>>>(Wih1, wih1bf);
  tp_bf16_k<<<dim3(8, 16), 256, 0, stream>>>(W_root, wroott, 512, 256);
  tp_bf16_k<<<dim3(8, 8), 256, 0, stream>>>(gc_W1, gcW1t, 256, 256);
  tp_bf16_k<<<dim3(8, 8), 256, 0, stream>>>(gc_W2, gcW2t, 256, 256);
  tp_bf16_k<<<dim3(24, 24), 256, 0, stream>>>(Wm, Wmt, 768, 768);
  tp_bf16_k<<<dim3(8, 24), 256, 0, stream>>>(Wl, Wlt, 768, 256);
  tp_bf16_k<<<dim3(4, 16), 256, 0, stream>>>(W_scalar, wscT, 512, 128);
  wrel_k<<<512, 256, 0, stream>>>(basis, comp, wrel2t);

  // --- layer 0 ---
  gemm_bf16_nt<true, false, false, false><<<dim3(8, 64, 2), 256, 0, stream>>>(
      ubf, wih0bf, b0, gates, 8192, 1024, 1024, 0L, 1048576L, 8388608L, 1024L);
  lstm4_k<<<128, 1024, 0, stream>>>(gates, wq, fsc, f0bf);

  // --- layer 1 ---
  gemm_bf16_nt<true, false, false, false><<<dim3(8, 64, 2), 256, 0, stream>>>(
      f0bf, wih1bf, b1, gates, 8192, 1024, 512, 0L, 524288L, 8388608L, 1024L);
  lstm4_k<<<128, 1024, 0, stream>>>(gates, wq + 131072, fsc + 2048, featsbf);

  // --- edge attention scores ---
  gemm_bf16_nt<false, false, false, false><<<dim3(1, 64, 1), 256, 0, stream>>>(
      featsbf, wscT, nullptr, scaleb, 8192, 128, 512, 0L, 0L, 0L, 0L);
  edge_softmax_k<<<8192, 128, 0, stream>>>(scaleb, scoresb);

  // --- node features (b-major) + RGCN ---
  xbuf_k<<<8192, 256, 0, stream>>>(featsbf, xbf);
  gemm_bf16_nt<true, false, false, false><<<dim3(2, 64, 1), 256, 0, stream>>>(
      xbf, wroott, b_rgcn, hroot, 8192, 256, 512, 0L, 0L, 0L, 0L);
  gemm_bf16_nt<false, false, false, false><<<dim3(16, 64, 1), 256, 0, stream>>>(
      xbf, wrel2t, nullptr, xrel, 8192, 2048, 512, 0L, 0L, 0L, 0L);
  rgcn_gather_k<<<8192, 256, 0, stream>>>(xrel, scoresb, hroot, speakers, hb, hbf);

  // --- GraphConv ---
  agg_k<<<8192, 256, 0, stream>>>(hb, aggbf);
  gemm_bf16_nt<true, false, false, false><<<dim3(2, 64, 1), 256, 0, stream>>>(
      hbf, gcW1t, gc_b, h2b, 8192, 256, 256, 0L, 0L, 0L, 0L);
  gemm_bf16_nt<false, true, false, false><<<dim3(2, 64, 1), 256, 0, stream>>>(
      aggbf, gcW2t, nullptr, h2b, 8192, 256, 256, 0L, 0L, 0L, 0L);

  // --- matching attention ---
  em_k<<<8192, 256, 0, stream>>>(xbf, h2b, embf);
  gemm_bf16_nt<true, false, false, true><<<dim3(6, 64, 1), 256, 0, stream>>>(
      embf, Wmt, bm, xtrbf, 8192, 768, 768, 0L, 0L, 0L, 0L);
  emt_k<<<dim3(24, 4, 64), 256, 0, stream>>>(embf, emT);
  gemm_bf16_nt<false, false, false, false><<<dim3(1, 1, 64), 256, 0, stream>>>(
      xtrbf, embf, nullptr, logitsb, 128, 128, 768, 98304L, 98304L, 16384L, 0L);
  match_softmax_k<<<8192, 128, 0, stream>>>(logitsb, umask, abf);
  gemm_bf16_nt<false, false, false, true><<<dim3(6, 1, 64), 256, 0, stream>>>(
      abf, emT, nullptr, attbf, 128, 768, 128, 16384L, 98304L, 98304L, 0L);

  // --- classifier ---
  gemm_bf16_nt<true, false, true, false><<<dim3(2, 64, 1), 256, 0, stream>>>(
      attbf, Wlt, bl, hiddenb, 8192, 256, 768, 0L, 0L, 0L, 0L);
  final_k<<<2048, 256, 0, stream>>>(hiddenb, Wsw, bsw, (float*)d_out);
}